// Round 4
// baseline (601.096 us; speedup 1.0000x reference)
//
#include <hip/hip_runtime.h>
#include <hip/hip_bf16.h>
#include <stdint.h>

// Problem constants
#define B_    8
#define T_    4
#define NLAT  64
#define NMED  2048
#define NKV   2112      // NMED + NLAT
#define D_    1024
#define HEADS 16
#define HD    64
#define ADIM  1024
#define BT    32        // B_*T_

#define GK    1024      // kv-GEMM K
#define GN    2048      // kv-GEMM N
#define GM    67584     // BT*NKV
#define MT2   264       // GM/256
#define NSLC  32        // GK/32

typedef __attribute__((ext_vector_type(8))) short bf16x8;
typedef __attribute__((ext_vector_type(4))) float f32x4;

__device__ __forceinline__ ushort f2bf(float f) {
  union { float f; uint32_t u; } v; v.f = f;
  return (ushort)((v.u + 0x7fff + ((v.u >> 16) & 1)) >> 16);
}

__device__ __forceinline__ void gload_lds16(const void* g, void* l) {
  __builtin_amdgcn_global_load_lds(
      (const __attribute__((address_space(1))) void*)g,
      (__attribute__((address_space(3))) void*)l, 16, 0, 0);
}

__device__ __forceinline__ f32x4 mfma16(bf16x8 a, bf16x8 b, f32x4 c) {
  return __builtin_amdgcn_mfma_f32_16x16x32_bf16(a, b, c, 0, 0, 0);
}

// ---------------------------------------------------------------------------
// Weight transpose + f32->bf16: dst[n][k] = src[k][n].  src [K][Nm], 64x64 tiles.
__global__ __launch_bounds__(256) void wtrans(const float* __restrict__ src,
                                              ushort* __restrict__ dst,
                                              int K, int Nm) {
  __shared__ float t[64][65];
  const int tr = blockIdx.y, tc = blockIdx.x;
  const int c = threadIdx.x & 63;
  const int r4 = threadIdx.x >> 6;
#pragma unroll
  for (int rr = 0; rr < 16; ++rr) {
    int r = r4 + rr * 4;
    t[r][c] = src[(size_t)(tr * 64 + r) * Nm + tc * 64 + c];
  }
  __syncthreads();
#pragma unroll
  for (int rr = 0; rr < 16; ++rr) {
    int n = r4 + rr * 4;
    dst[(size_t)(tc * 64 + n) * K + tr * 64 + c] = f2bf(t[c][n]);
  }
}

// ---------------------------------------------------------------------------
// LayerNorm -> bf16, writing concatenated kv_in.
__global__ __launch_bounds__(256) void ln_kernel(
    const float* __restrict__ lat, const float* __restrict__ x,
    const float* __restrict__ lnl_w, const float* __restrict__ lnl_b,
    const float* __restrict__ lnm_w, const float* __restrict__ lnm_b,
    ushort* __restrict__ kvin) {
  const int row = blockIdx.x;
  const int bt = row / NKV;
  const int j = row - bt * NKV;
  const float* src;
  const float* w;
  const float* bb;
  if (j < NMED) {
    src = x + ((size_t)bt * NMED + j) * D_;
    w = lnm_w; bb = lnm_b;
  } else {
    src = lat + ((size_t)bt * NLAT + (j - NMED)) * D_;
    w = lnl_w; bb = lnl_b;
  }
  const int tid = threadIdx.x;
  float4 v = ((const float4*)src)[tid];
  float s = v.x + v.y + v.z + v.w;
  float s2 = v.x * v.x + v.y * v.y + v.z * v.z + v.w * v.w;
#pragma unroll
  for (int off = 1; off < 64; off <<= 1) {
    s += __shfl_xor(s, off, 64);
    s2 += __shfl_xor(s2, off, 64);
  }
  __shared__ float red[8];
  const int wave = tid >> 6;
  if ((tid & 63) == 0) { red[wave] = s; red[4 + wave] = s2; }
  __syncthreads();
  float S = red[0] + red[1] + red[2] + red[3];
  float S2 = red[4] + red[5] + red[6] + red[7];
  const float inv = 1.f / (float)D_;
  float mu = S * inv;
  float var = S2 * inv - mu * mu;
  float rs = rsqrtf(var + 1e-5f);
  float4 wv = ((const float4*)w)[tid];
  float4 bv = ((const float4*)bb)[tid];
  ushort4 ov;
  ov.x = f2bf((v.x - mu) * rs * wv.x + bv.x);
  ov.y = f2bf((v.y - mu) * rs * wv.y + bv.y);
  ov.z = f2bf((v.z - mu) * rs * wv.z + bv.z);
  ov.w = f2bf((v.w - mu) * rs * wv.w + bv.w);
  ((ushort4*)(kvin + (size_t)row * D_))[tid] = ov;
}

// ---------------------------------------------------------------------------
// m97-structure 128x128 GEMM — used for the two SMALL GEMMs (q, out).
// AMODE:  0 = direct rows; 1 = q-GEMM remap (row -> kvin[bt*2112+2048+local])
// OUTMODE:1 = bf16 * 0.125 (q scale); 2 = f32 + bias
template <int AMODE, int OUTMODE>
__global__ __launch_bounds__(256) void gemm_bt(const ushort* __restrict__ A,
                                               const ushort* __restrict__ Bt,
                                               void* __restrict__ C,
                                               const float* __restrict__ bias,
                                               int M, int N, int K, int ldc) {
  __shared__ ushort lsA[128 * 32];
  __shared__ ushort lsB[128 * 32];
  const int tid = threadIdx.x;
  const int lane = tid & 63;
  const int wave = tid >> 6;
  const int brow = blockIdx.y * 128;
  const int bcol = blockIdx.x * 128;
  const int wr = (wave >> 1) * 64;
  const int wc = (wave & 1) * 64;
  const int lr = lane & 15;
  const int lk = (lane >> 4) * 8;

  f32x4 acc[4][4];
#pragma unroll
  for (int m = 0; m < 4; ++m)
#pragma unroll
    for (int n = 0; n < 4; ++n) acc[m][n] = (f32x4){0.f, 0.f, 0.f, 0.f};

  const int wbase = (tid & 192) * 16;

  for (int k0 = 0; k0 < K; k0 += 32) {
#pragma unroll
    for (int i = 0; i < 2; ++i) {
      int idx = i * 256 + tid;
      int r = idx >> 2;
      int cc = (idx & 3) * 8;
      long arow;
      if (AMODE == 1) {
        int gr = brow + r;
        arow = (long)(gr >> 6) * NKV + NMED + (gr & 63);
      } else {
        arow = brow + r;
      }
      gload_lds16(A + arow * (long)K + k0 + cc, (char*)lsA + i * 4096 + wbase);
      gload_lds16(Bt + (long)(bcol + r) * K + k0 + cc, (char*)lsB + i * 4096 + wbase);
    }
    __syncthreads();

    bf16x8 af[4], bf[4];
#pragma unroll
    for (int m = 0; m < 4; ++m)
      af[m] = *(const bf16x8*)&lsA[(wr + m * 16 + lr) * 32 + lk];
#pragma unroll
    for (int n = 0; n < 4; ++n)
      bf[n] = *(const bf16x8*)&lsB[(wc + n * 16 + lr) * 32 + lk];
#pragma unroll
    for (int m = 0; m < 4; ++m)
#pragma unroll
      for (int n = 0; n < 4; ++n) acc[m][n] = mfma16(af[m], bf[n], acc[m][n]);
    __syncthreads();
  }

#pragma unroll
  for (int m = 0; m < 4; ++m) {
#pragma unroll
    for (int n = 0; n < 4; ++n) {
      int row0 = brow + wr + m * 16 + (lane >> 4) * 4;
      int col = bcol + wc + n * 16 + lr;
#pragma unroll
      for (int r = 0; r < 4; ++r) {
        long off = (long)(row0 + r) * ldc + col;
        float v = acc[m][n][r];
        if (OUTMODE == 1) ((ushort*)C)[off] = f2bf(v * 0.125f);
        else ((float*)C)[off] = v + bias[col];
      }
    }
  }
}

// ---------------------------------------------------------------------------
// kv-GEMM: 256x256 tile, 8 waves of 128x64 (2M x 4N), K streamed as 32 slices
// of BK=32 through a 4-slot LDS ring (128 KB dynamic, 1 block/CU).
// Stage-ahead distance 3; one counted vmcnt(8) per slice (never 0); two
// phases/slice, each {ds_read || 2 gload_lds -> barrier -> lgkmcnt(0) ->
// setprio(1) -> 16 MFMA -> setprio(0) -> barrier}.  Chunk-XOR swizzle
// both-sides, swapped-operand MFMA, ushort4 stores, XCD swizzle (2112=8*264).
__global__ __launch_bounds__(512, 2) void gemm256(const ushort* __restrict__ A,
                                                  const ushort* __restrict__ Bt,
                                                  ushort* __restrict__ C) {
  extern __shared__ __align__(16) char smem[];  // 4 slots x (16KB A + 16KB B)
  const int tid = threadIdx.x;
  const int lane = tid & 63;
  const int wv = tid >> 6;   // 0..7
  const int wm = wv >> 2;    // 0..1  (M half: 128 rows)
  const int wn = wv & 3;     // 0..3  (N quarter: 64 cols)
  const int lr = lane & 15;
  const int lg = lane >> 4;

  // bijective XCD swizzle: nwg = 2112 = 8 * 264
  const int g = blockIdx.x;
  const int v = (g & 7) * MT2 + (g >> 3);
  const int bx = v & 7;        // N tile
  const int by = v >> 3;       // M tile
  const long brow = (long)by * 256;
  const int bcol = bx * 256;

  const int pcx = lg ^ ((lr >> 1) & 3);  // physical 16B-chunk for frag reads

  f32x4 acc[8][4];
#pragma unroll
  for (int m = 0; m < 8; ++m)
#pragma unroll
    for (int n = 0; n < 4; ++n) acc[m][n] = (f32x4){0.f, 0.f, 0.f, 0.f};

  // staging decode (both-sides swizzle): slot s -> row = s>>2,
  // logical chunk = (s&3) ^ ((s>>3)&3), LDS byte base = (s&~63)*16
  const int s0 = tid, s1 = 512 + tid;
  const int r0 = s0 >> 2, r1 = s1 >> 2;
  const int c0 = (s0 & 3) ^ ((s0 >> 3) & 3);
  const int c1 = (s1 & 3) ^ ((s1 >> 3) & 3);
  const int o0 = (s0 & ~63) * 16;
  const int o1 = (s1 & ~63) * 16;

#define STAGE_A(slc, slot)                                                     \
  {                                                                            \
    long k0 = (long)(slc) * 32;                                                \
    char* db = smem + (slot) * 32768;                                          \
    gload_lds16(A + (brow + r0) * (long)GK + k0 + c0 * 8, db + o0);            \
    gload_lds16(A + (brow + r1) * (long)GK + k0 + c1 * 8, db + o1);            \
  }
#define STAGE_B(slc, slot)                                                     \
  {                                                                            \
    long k0 = (long)(slc) * 32;                                                \
    char* db = smem + (slot) * 32768 + 16384;                                  \
    gload_lds16(Bt + (long)(bcol + r0) * GK + k0 + c0 * 8, db + o0);           \
    gload_lds16(Bt + (long)(bcol + r1) * GK + k0 + c1 * 8, db + o1);           \
  }

  // prologue: slices 0,1,2 (12 loads); wait until slice 0 landed (8 in flight)
  STAGE_A(0, 0); STAGE_B(0, 0);
  STAGE_A(1, 1); STAGE_B(1, 1);
  STAGE_A(2, 2); STAGE_B(2, 2);
  asm volatile("s_waitcnt vmcnt(8)" ::: "memory");
  __builtin_amdgcn_s_barrier();
  __builtin_amdgcn_sched_barrier(0);

  for (int t = 0; t < NSLC; ++t) {
    const char* sA = smem + (t & 3) * 32768;
    const char* sB = sA + 16384;
    const int ts = (t + 3 < NSLC) ? t + 3 : t;  // dummy re-stage at tail
    const int wslot = (t + 3) & 3;              // == (t-1)&3: free (reads drained)
    bf16x8 af[4], bf[4];

    // ---- phase 0: m-frags 0..3, all n ----
#pragma unroll
    for (int m = 0; m < 4; ++m) {
      int row = wm * 128 + m * 16 + lr;
      af[m] = *(const bf16x8*)(sA + row * 64 + pcx * 16);
    }
#pragma unroll
    for (int n = 0; n < 4; ++n) {
      int row = wn * 64 + n * 16 + lr;
      bf[n] = *(const bf16x8*)(sB + row * 64 + pcx * 16);
    }
    STAGE_A(ts, wslot);
    __builtin_amdgcn_s_barrier();
    asm volatile("s_waitcnt lgkmcnt(0)" ::: "memory");
    __builtin_amdgcn_sched_barrier(0);
    __builtin_amdgcn_s_setprio(1);
#pragma unroll
    for (int m = 0; m < 4; ++m)
#pragma unroll
      for (int n = 0; n < 4; ++n)
        acc[m][n] = mfma16(bf[n], af[m], acc[m][n]);   // swapped operands
    __builtin_amdgcn_s_setprio(0);
    __builtin_amdgcn_sched_barrier(0);
    __builtin_amdgcn_s_barrier();

    // ---- phase 1: m-frags 4..7, bf reused in regs ----
#pragma unroll
    for (int m = 0; m < 4; ++m) {
      int row = wm * 128 + (m + 4) * 16 + lr;
      af[m] = *(const bf16x8*)(sA + row * 64 + pcx * 16);
    }
    STAGE_B(ts, wslot);
    // counted wait: slice t+1 landed (oldest 4 of 12 outstanding); t+2,t+3 in flight
    asm volatile("s_waitcnt vmcnt(8)" ::: "memory");
    __builtin_amdgcn_s_barrier();
    asm volatile("s_waitcnt lgkmcnt(0)" ::: "memory");
    __builtin_amdgcn_sched_barrier(0);
    __builtin_amdgcn_s_setprio(1);
#pragma unroll
    for (int m = 0; m < 4; ++m)
#pragma unroll
      for (int n = 0; n < 4; ++n)
        acc[m + 4][n] = mfma16(bf[n], af[m], acc[m + 4][n]);
    __builtin_amdgcn_s_setprio(0);
    __builtin_amdgcn_sched_barrier(0);
    __builtin_amdgcn_s_barrier();
  }
#undef STAGE_A
#undef STAGE_B

  // epilogue: lane owns row ...+lr, 4 consecutive cols per frag (ushort4)
#pragma unroll
  for (int m = 0; m < 8; ++m) {
    long row = brow + wm * 128 + m * 16 + lr;
    ushort* crow = C + row * GN + bcol + wn * 64 + lg * 4;
#pragma unroll
    for (int n = 0; n < 4; ++n) {
      ushort4 o;
      o.x = f2bf(acc[m][n][0]);
      o.y = f2bf(acc[m][n][1]);
      o.z = f2bf(acc[m][n][2]);
      o.w = f2bf(acc[m][n][3]);
      *(ushort4*)(crow + n * 16) = o;
    }
  }
}

// ---------------------------------------------------------------------------
// Flash attention: one block per (bt, h). 4 waves x 16 q-rows. 33 j-tiles of 64.
__global__ __launch_bounds__(256) void attn_kernel(const ushort* __restrict__ q,
                                                   const ushort* __restrict__ kv,
                                                   ushort* __restrict__ o) {
  const int blk = blockIdx.x;
  const int bt = blk >> 4;
  const int h = blk & 15;
  const int tid = threadIdx.x;
  const int wave = tid >> 6;
  const int lane = tid & 63;
  const int lr = lane & 15;
  const int lg = lane >> 4;

  __shared__ ushort vt[64][72];
  __shared__ ushort pl[4][16][72];

  const ushort* qbase = q + (size_t)(bt * 64 + wave * 16) * ADIM + h * HD;
  bf16x8 qf[2];
#pragma unroll
  for (int ks = 0; ks < 2; ++ks)
    qf[ks] = *(const bf16x8*)(qbase + (size_t)lr * ADIM + ks * 32 + lg * 8);

  const ushort* kvb = kv + (size_t)bt * NKV * 2048;

  f32x4 accO[4];
#pragma unroll
  for (int n = 0; n < 4; ++n) accO[n] = (f32x4){0.f, 0.f, 0.f, 0.f};
  float mrun[4] = {-1e30f, -1e30f, -1e30f, -1e30f};
  float lrun[4] = {0.f, 0.f, 0.f, 0.f};

  for (int jt = 0; jt < NKV / 64; ++jt) {
    const int j0 = jt * 64;
    __syncthreads();

    {
      int jj = tid >> 2;
      int dbase = (tid & 3) * 16;
#pragma unroll
      for (int half = 0; half < 2; ++half) {
        int d0 = dbase + half * 8;
        bf16x8 vv = *(const bf16x8*)(kvb + (size_t)(j0 + jj) * 2048 + ADIM + h * HD + d0);
#pragma unroll
        for (int e = 0; e < 8; ++e) vt[d0 + e][jj] = ((const ushort*)&vv)[e];
      }
    }

    f32x4 s[4];
#pragma unroll
    for (int nj = 0; nj < 4; ++nj) s[nj] = (f32x4){0.f, 0.f, 0.f, 0.f};
#pragma unroll
    for (int nj = 0; nj < 4; ++nj)
#pragma unroll
      for (int ks = 0; ks < 2; ++ks) {
        bf16x8 kf = *(const bf16x8*)(kvb + (size_t)(j0 + nj * 16 + lr) * 2048 +
                                     h * HD + ks * 32 + lg * 8);
        s[nj] = mfma16(qf[ks], kf, s[nj]);
      }

    float mt[4], corr[4], psum[4];
#pragma unroll
    for (int r = 0; r < 4; ++r)
      mt[r] = fmaxf(fmaxf(s[0][r], s[1][r]), fmaxf(s[2][r], s[3][r]));
#pragma unroll
    for (int off = 1; off < 16; off <<= 1)
#pragma unroll
      for (int r = 0; r < 4; ++r) mt[r] = fmaxf(mt[r], __shfl_xor(mt[r], off, 64));
#pragma unroll
    for (int r = 0; r < 4; ++r) {
      float mn = fmaxf(mrun[r], mt[r]);
      corr[r] = __expf(mrun[r] - mn);
      mrun[r] = mn;
      psum[r] = 0.f;
    }
#pragma unroll
    for (int nj = 0; nj < 4; ++nj)
#pragma unroll
      for (int r = 0; r < 4; ++r) {
        float pv = __expf(s[nj][r] - mrun[r]);
        s[nj][r] = pv;
        psum[r] += pv;
      }
#pragma unroll
    for (int off = 1; off < 16; off <<= 1)
#pragma unroll
      for (int r = 0; r < 4; ++r) psum[r] += __shfl_xor(psum[r], off, 64);
#pragma unroll
    for (int r = 0; r < 4; ++r) lrun[r] = lrun[r] * corr[r] + psum[r];
#pragma unroll
    for (int n = 0; n < 4; ++n)
#pragma unroll
      for (int r = 0; r < 4; ++r) accO[n][r] *= corr[r];

#pragma unroll
    for (int nj = 0; nj < 4; ++nj)
#pragma unroll
      for (int r = 0; r < 4; ++r)
        pl[wave][lg * 4 + r][nj * 16 + lr] = f2bf(s[nj][r]);
    __syncthreads();

    bf16x8 pf[2];
#pragma unroll
    for (int ks = 0; ks < 2; ++ks)
      pf[ks] = *(const bf16x8*)&pl[wave][lr][ks * 32 + lg * 8];
#pragma unroll
    for (int nd = 0; nd < 4; ++nd)
#pragma unroll
      for (int ks = 0; ks < 2; ++ks) {
        bf16x8 vf = *(const bf16x8*)&vt[nd * 16 + lr][ks * 32 + lg * 8];
        accO[nd] = mfma16(pf[ks], vf, accO[nd]);
      }
  }

#pragma unroll
  for (int nd = 0; nd < 4; ++nd)
#pragma unroll
    for (int r = 0; r < 4; ++r) {
      float vv = accO[nd][r] / lrun[r];
      int row = bt * 64 + wave * 16 + lg * 4 + r;
      o[(size_t)row * ADIM + h * HD + nd * 16 + lr] = f2bf(vv);
    }
}

// ---------------------------------------------------------------------------
extern "C" void kernel_launch(void* const* d_in, const int* in_sizes, int n_in,
                              void* d_out, int out_size, void* d_ws, size_t ws_size,
                              hipStream_t stream) {
  const float* latents = (const float*)d_in[0];
  const float* x = (const float*)d_in[1];
  const float* Wq = (const float*)d_in[2];
  const float* Wkv = (const float*)d_in[3];
  const float* Wout = (const float*)d_in[4];
  const float* bout = (const float*)d_in[5];
  const float* lnl_w = (const float*)d_in[6];
  const float* lnl_b = (const float*)d_in[7];
  const float* lnm_w = (const float*)d_in[8];
  const float* lnm_b = (const float*)d_in[9];

  char* ws = (char*)d_ws;
  size_t off = 0;
  auto alloc = [&](size_t bytes) -> void* {
    void* p = ws + off;
    off += (bytes + 255) & ~(size_t)255;
    return p;
  };
  ushort* kvin = (ushort*)alloc((size_t)BT * NKV * D_ * 2);
  ushort* kvo  = (ushort*)alloc((size_t)BT * NKV * 2048 * 2);
  ushort* qb   = (ushort*)alloc((size_t)BT * NLAT * ADIM * 2);
  ushort* ao   = (ushort*)alloc((size_t)BT * NLAT * ADIM * 2);
  ushort* WqT  = (ushort*)alloc((size_t)D_ * ADIM * 2);
  ushort* WkvT = (ushort*)alloc((size_t)D_ * 2 * ADIM * 2);
  ushort* WoutT = (ushort*)alloc((size_t)ADIM * D_ * 2);

  // 128 KB dynamic LDS for gemm256
  hipFuncSetAttribute((const void*)gemm256,
                      hipFuncAttributeMaxDynamicSharedMemorySize, 131072);

  // 1) weights -> bf16 B^T
  wtrans<<<dim3(ADIM / 64, D_ / 64), 256, 0, stream>>>(Wq, WqT, D_, ADIM);
  wtrans<<<dim3(2 * ADIM / 64, D_ / 64), 256, 0, stream>>>(Wkv, WkvT, D_, 2 * ADIM);
  wtrans<<<dim3(D_ / 64, ADIM / 64), 256, 0, stream>>>(Wout, WoutT, ADIM, D_);

  // 2) LN -> bf16 kv_in
  ln_kernel<<<BT * NKV, 256, 0, stream>>>(latents, x, lnl_w, lnl_b, lnm_w, lnm_b, kvin);

  // 3) q = lat_ln @ Wq (remapped A rows, 0.125 folded)
  gemm_bt<1, 1><<<dim3(ADIM / 128, BT * NLAT / 128), 256, 0, stream>>>(
      kvin, WqT, qb, nullptr, BT * NLAT, ADIM, D_, ADIM);

  // 4) kv = kv_in @ Wkv  — 256^2 ring-pipelined kernel (m201-style)
  gemm256<<<dim3(MT2 * 8), 512, 131072, stream>>>(kvin, WkvT, kvo);

  // 5) attention
  attn_kernel<<<BT * HEADS, 256, 0, stream>>>(qb, kvo, ao);

  // 6) out = ao @ Wout + bout
  gemm_bt<0, 2><<<dim3(D_ / 128, BT * NLAT / 128), 256, 0, stream>>>(
      ao, WoutT, d_out, bout, BT * NLAT, D_, ADIM, D_);
}

// Round 5
// 596.598 us; speedup vs baseline: 1.0075x; 1.0075x over previous
//
#include <hip/hip_runtime.h>
#include <hip/hip_bf16.h>
#include <stdint.h>

// Problem constants
#define B_    8
#define T_    4
#define NLAT  64
#define NMED  2048
#define NKV   2112      // NMED + NLAT
#define D_    1024
#define HEADS 16
#define HD    64
#define ADIM  1024
#define BT    32        // B_*T_

#define GK    1024      // kv-GEMM K
#define GN    2048      // kv-GEMM N
#define GM    67584     // BT*NKV
#define MT2   264       // GM/256
#define NSLC  32        // GK/32

typedef __attribute__((ext_vector_type(8))) short bf16x8;
typedef __attribute__((ext_vector_type(4))) float f32x4;

__device__ __forceinline__ ushort f2bf(float f) {
  union { float f; uint32_t u; } v; v.f = f;
  return (ushort)((v.u + 0x7fff + ((v.u >> 16) & 1)) >> 16);
}

__device__ __forceinline__ void gload_lds16(const void* g, void* l) {
  __builtin_amdgcn_global_load_lds(
      (const __attribute__((address_space(1))) void*)g,
      (__attribute__((address_space(3))) void*)l, 16, 0, 0);
}

__device__ __forceinline__ f32x4 mfma16(bf16x8 a, bf16x8 b, f32x4 c) {
  return __builtin_amdgcn_mfma_f32_16x16x32_bf16(a, b, c, 0, 0, 0);
}

// ---------------------------------------------------------------------------
// Weight transpose + f32->bf16: dst[n][k] = src[k][n].  src [K][Nm], 64x64 tiles.
__global__ __launch_bounds__(256) void wtrans(const float* __restrict__ src,
                                              ushort* __restrict__ dst,
                                              int K, int Nm) {
  __shared__ float t[64][65];
  const int tr = blockIdx.y, tc = blockIdx.x;
  const int c = threadIdx.x & 63;
  const int r4 = threadIdx.x >> 6;
#pragma unroll
  for (int rr = 0; rr < 16; ++rr) {
    int r = r4 + rr * 4;
    t[r][c] = src[(size_t)(tr * 64 + r) * Nm + tc * 64 + c];
  }
  __syncthreads();
#pragma unroll
  for (int rr = 0; rr < 16; ++rr) {
    int n = r4 + rr * 4;
    dst[(size_t)(tc * 64 + n) * K + tr * 64 + c] = f2bf(t[c][n]);
  }
}

// ---------------------------------------------------------------------------
// LayerNorm -> bf16, writing concatenated kv_in.
__global__ __launch_bounds__(256) void ln_kernel(
    const float* __restrict__ lat, const float* __restrict__ x,
    const float* __restrict__ lnl_w, const float* __restrict__ lnl_b,
    const float* __restrict__ lnm_w, const float* __restrict__ lnm_b,
    ushort* __restrict__ kvin) {
  const int row = blockIdx.x;
  const int bt = row / NKV;
  const int j = row - bt * NKV;
  const float* src;
  const float* w;
  const float* bb;
  if (j < NMED) {
    src = x + ((size_t)bt * NMED + j) * D_;
    w = lnm_w; bb = lnm_b;
  } else {
    src = lat + ((size_t)bt * NLAT + (j - NMED)) * D_;
    w = lnl_w; bb = lnl_b;
  }
  const int tid = threadIdx.x;
  float4 v = ((const float4*)src)[tid];
  float s = v.x + v.y + v.z + v.w;
  float s2 = v.x * v.x + v.y * v.y + v.z * v.z + v.w * v.w;
#pragma unroll
  for (int off = 1; off < 64; off <<= 1) {
    s += __shfl_xor(s, off, 64);
    s2 += __shfl_xor(s2, off, 64);
  }
  __shared__ float red[8];
  const int wave = tid >> 6;
  if ((tid & 63) == 0) { red[wave] = s; red[4 + wave] = s2; }
  __syncthreads();
  float S = red[0] + red[1] + red[2] + red[3];
  float S2 = red[4] + red[5] + red[6] + red[7];
  const float inv = 1.f / (float)D_;
  float mu = S * inv;
  float var = S2 * inv - mu * mu;
  float rs = rsqrtf(var + 1e-5f);
  float4 wv = ((const float4*)w)[tid];
  float4 bv = ((const float4*)bb)[tid];
  ushort4 ov;
  ov.x = f2bf((v.x - mu) * rs * wv.x + bv.x);
  ov.y = f2bf((v.y - mu) * rs * wv.y + bv.y);
  ov.z = f2bf((v.z - mu) * rs * wv.z + bv.z);
  ov.w = f2bf((v.w - mu) * rs * wv.w + bv.w);
  ((ushort4*)(kvin + (size_t)row * D_))[tid] = ov;
}

// ---------------------------------------------------------------------------
// m97-structure 128x128 GEMM — used for the two SMALL GEMMs (q, out).
// AMODE:  0 = direct rows; 1 = q-GEMM remap (row -> kvin[bt*2112+2048+local])
// OUTMODE:1 = bf16 * 0.125 (q scale); 2 = f32 + bias
template <int AMODE, int OUTMODE>
__global__ __launch_bounds__(256) void gemm_bt(const ushort* __restrict__ A,
                                               const ushort* __restrict__ Bt,
                                               void* __restrict__ C,
                                               const float* __restrict__ bias,
                                               int M, int N, int K, int ldc) {
  __shared__ ushort lsA[128 * 32];
  __shared__ ushort lsB[128 * 32];
  const int tid = threadIdx.x;
  const int lane = tid & 63;
  const int wave = tid >> 6;
  const int brow = blockIdx.y * 128;
  const int bcol = blockIdx.x * 128;
  const int wr = (wave >> 1) * 64;
  const int wc = (wave & 1) * 64;
  const int lr = lane & 15;
  const int lk = (lane >> 4) * 8;

  f32x4 acc[4][4];
#pragma unroll
  for (int m = 0; m < 4; ++m)
#pragma unroll
    for (int n = 0; n < 4; ++n) acc[m][n] = (f32x4){0.f, 0.f, 0.f, 0.f};

  const int wbase = (tid & 192) * 16;

  for (int k0 = 0; k0 < K; k0 += 32) {
#pragma unroll
    for (int i = 0; i < 2; ++i) {
      int idx = i * 256 + tid;
      int r = idx >> 2;
      int cc = (idx & 3) * 8;
      long arow;
      if (AMODE == 1) {
        int gr = brow + r;
        arow = (long)(gr >> 6) * NKV + NMED + (gr & 63);
      } else {
        arow = brow + r;
      }
      gload_lds16(A + arow * (long)K + k0 + cc, (char*)lsA + i * 4096 + wbase);
      gload_lds16(Bt + (long)(bcol + r) * K + k0 + cc, (char*)lsB + i * 4096 + wbase);
    }
    __syncthreads();

    bf16x8 af[4], bf[4];
#pragma unroll
    for (int m = 0; m < 4; ++m)
      af[m] = *(const bf16x8*)&lsA[(wr + m * 16 + lr) * 32 + lk];
#pragma unroll
    for (int n = 0; n < 4; ++n)
      bf[n] = *(const bf16x8*)&lsB[(wc + n * 16 + lr) * 32 + lk];
#pragma unroll
    for (int m = 0; m < 4; ++m)
#pragma unroll
      for (int n = 0; n < 4; ++n) acc[m][n] = mfma16(af[m], bf[n], acc[m][n]);
    __syncthreads();
  }

#pragma unroll
  for (int m = 0; m < 4; ++m) {
#pragma unroll
    for (int n = 0; n < 4; ++n) {
      int row0 = brow + wr + m * 16 + (lane >> 4) * 4;
      int col = bcol + wc + n * 16 + lr;
#pragma unroll
      for (int r = 0; r < 4; ++r) {
        long off = (long)(row0 + r) * ldc + col;
        float v = acc[m][n][r];
        if (OUTMODE == 1) ((ushort*)C)[off] = f2bf(v * 0.125f);
        else ((float*)C)[off] = v + bias[col];
      }
    }
  }
}

// ---------------------------------------------------------------------------
// kv-GEMM: 256x256 tile, 8 waves of 128x64 (2M x 4N), BK=32, 4-slot LDS ring
// (128 KB), stage-ahead 3, vmcnt(8) per slice.  NEW vs R4: cross-phase
// ds_read pipelining — every phase's MFMA runs with the NEXT phase's 4-8
// ds_reads outstanding, waited by COUNTED lgkmcnt(4/8) (never 0 in loop).
// Register frag sets a0/a1 + b0/b1 double-buffered; slices unrolled x2 so
// all indexing is static (no scratch).  Chunk-XOR swizzle both-sides,
// swapped-operand MFMA, ushort4 stores, XCD swizzle (2112 = 8*264).
__global__ __launch_bounds__(512, 2) void gemm256(const ushort* __restrict__ A,
                                                  const ushort* __restrict__ Bt,
                                                  ushort* __restrict__ C) {
  extern __shared__ __align__(16) char smem[];  // 4 slots x (16KB A + 16KB B)
  const int tid = threadIdx.x;
  const int lane = tid & 63;
  const int wv = tid >> 6;   // 0..7
  const int wm = wv >> 2;    // 0..1  (M half: 128 rows)
  const int wn = wv & 3;     // 0..3  (N quarter: 64 cols)
  const int lr = lane & 15;
  const int lg = lane >> 4;

  // bijective XCD swizzle: nwg = 2112 = 8 * 264
  const int g = blockIdx.x;
  const int v = (g & 7) * MT2 + (g >> 3);
  const int bx = v & 7;        // N tile
  const int by = v >> 3;       // M tile
  const long brow = (long)by * 256;
  const int bcol = bx * 256;

  const int pcx = lg ^ ((lr >> 1) & 3);  // physical 16B-chunk for frag reads
  const int rbA = wm * 128 + lr;         // per-lane A row base
  const int rbB = wn * 64 + lr;          // per-lane B row base

  f32x4 acc[8][4];
#pragma unroll
  for (int m = 0; m < 8; ++m)
#pragma unroll
    for (int n = 0; n < 4; ++n) acc[m][n] = (f32x4){0.f, 0.f, 0.f, 0.f};

  // staging decode (both-sides swizzle): slot s -> row = s>>2,
  // logical chunk = (s&3) ^ ((s>>3)&3), LDS byte base = (s&~63)*16
  const int s0 = tid, s1 = 512 + tid;
  const int r0 = s0 >> 2, r1 = s1 >> 2;
  const int c0 = (s0 & 3) ^ ((s0 >> 3) & 3);
  const int c1 = (s1 & 3) ^ ((s1 >> 3) & 3);
  const int o0 = (s0 & ~63) * 16;
  const int o1 = (s1 & ~63) * 16;

#define STAGE_A(slc, slot)                                                     \
  {                                                                            \
    long k0 = (long)(slc) * 32;                                                \
    char* db = smem + (slot) * 32768;                                          \
    gload_lds16(A + (brow + r0) * (long)GK + k0 + c0 * 8, db + o0);            \
    gload_lds16(A + (brow + r1) * (long)GK + k0 + c1 * 8, db + o1);            \
  }
#define STAGE_B(slc, slot)                                                     \
  {                                                                            \
    long k0 = (long)(slc) * 32;                                                \
    char* db = smem + (slot) * 32768 + 16384;                                  \
    gload_lds16(Bt + (long)(bcol + r0) * GK + k0 + c0 * 8, db + o0);           \
    gload_lds16(Bt + (long)(bcol + r1) * GK + k0 + c1 * 8, db + o1);           \
  }

  bf16x8 a0[4], a1[4], b0[4], b1[4];

  // prologue: slices 0,1,2 staged (12 loads); slice 0 landed after vmcnt(8)
  STAGE_A(0, 0); STAGE_B(0, 0);
  STAGE_A(1, 1); STAGE_B(1, 1);
  STAGE_A(2, 2); STAGE_B(2, 2);
  asm volatile("s_waitcnt vmcnt(8)" ::: "memory");
  __builtin_amdgcn_s_barrier();
  // issue slice-0 a0/b0 reads (8) — drained by first phase's lgkmcnt(4)
#pragma unroll
  for (int m = 0; m < 4; ++m)
    a0[m] = *(const bf16x8*)(smem + (rbA + m * 16) * 64 + pcx * 16);
#pragma unroll
  for (int n = 0; n < 4; ++n)
    b0[n] = *(const bf16x8*)(smem + 16384 + (rbB + n * 16) * 64 + pcx * 16);
  __builtin_amdgcn_sched_barrier(0);

  // SLICE(T, BCUR, BNXT): phase0 uses a0+BCUR, phase1 uses a1+BCUR and
  // issues next-slice reads into a0+BNXT.
#define SLICE(T, BCUR, BNXT)                                                   \
  {                                                                            \
    const int t_ = (T);                                                        \
    const char* sA_ = smem + (t_ & 3) * 32768;                                 \
    const int ts_ = (t_ + 3 < NSLC) ? t_ + 3 : t_;                             \
    const int ws_ = (t_ + 3) & 3;                                              \
    /* ---- phase 0 ---- */                                                    \
    _Pragma("unroll")                                                          \
    for (int m = 0; m < 4; ++m)                                                \
      a1[m] = *(const bf16x8*)(sA_ + (rbA + (m + 4) * 16) * 64 + pcx * 16);    \
    STAGE_A(ts_, ws_);                                                         \
    __builtin_amdgcn_sched_barrier(0);                                         \
    __builtin_amdgcn_s_barrier();                                              \
    asm volatile("s_waitcnt lgkmcnt(4)" ::: "memory");                         \
    __builtin_amdgcn_sched_barrier(0);                                         \
    __builtin_amdgcn_s_setprio(1);                                             \
    _Pragma("unroll")                                                          \
    for (int m = 0; m < 4; ++m)                                                \
      _Pragma("unroll")                                                        \
      for (int n = 0; n < 4; ++n)                                              \
        acc[m][n] = mfma16(BCUR[n], a0[m], acc[m][n]);                         \
    __builtin_amdgcn_s_setprio(0);                                             \
    __builtin_amdgcn_sched_barrier(0);                                         \
    __builtin_amdgcn_s_barrier();                                              \
    /* ---- phase 1 ---- */                                                    \
    STAGE_B(ts_, ws_);                                                         \
    asm volatile("s_waitcnt vmcnt(8)" ::: "memory");                           \
    __builtin_amdgcn_sched_barrier(0);                                         \
    __builtin_amdgcn_s_barrier();                                              \
    {                                                                          \
      const int tn_ = (t_ + 1 < NSLC) ? t_ + 1 : t_;                           \
      const char* nA_ = smem + (tn_ & 3) * 32768;                              \
      const char* nB_ = nA_ + 16384;                                           \
      _Pragma("unroll")                                                        \
      for (int m = 0; m < 4; ++m)                                              \
        a0[m] = *(const bf16x8*)(nA_ + (rbA + m * 16) * 64 + pcx * 16);        \
      _Pragma("unroll")                                                        \
      for (int n = 0; n < 4; ++n)                                              \
        BNXT[n] = *(const bf16x8*)(nB_ + (rbB + n * 16) * 64 + pcx * 16);      \
    }                                                                          \
    __builtin_amdgcn_sched_barrier(0);                                         \
    asm volatile("s_waitcnt lgkmcnt(8)" ::: "memory");                         \
    __builtin_amdgcn_sched_barrier(0);                                         \
    __builtin_amdgcn_s_setprio(1);                                             \
    _Pragma("unroll")                                                          \
    for (int m = 0; m < 4; ++m)                                                \
      _Pragma("unroll")                                                        \
      for (int n = 0; n < 4; ++n)                                              \
        acc[m + 4][n] = mfma16(BCUR[n], a1[m], acc[m + 4][n]);                 \
    __builtin_amdgcn_s_setprio(0);                                             \
    __builtin_amdgcn_sched_barrier(0);                                         \
    __builtin_amdgcn_s_barrier();                                              \
  }

  for (int t = 0; t < NSLC; t += 2) {
    SLICE(t, b0, b1);
    SLICE(t + 1, b1, b0);
  }
#undef SLICE
#undef STAGE_A
#undef STAGE_B

  // epilogue: lane owns row ...+lr, 4 consecutive cols per frag (ushort4)
#pragma unroll
  for (int m = 0; m < 8; ++m) {
    long row = brow + wm * 128 + m * 16 + lr;
    ushort* crow = C + row * GN + bcol + wn * 64 + lg * 4;
#pragma unroll
    for (int n = 0; n < 4; ++n) {
      ushort4 o;
      o.x = f2bf(acc[m][n][0]);
      o.y = f2bf(acc[m][n][1]);
      o.z = f2bf(acc[m][n][2]);
      o.w = f2bf(acc[m][n][3]);
      *(ushort4*)(crow + n * 16) = o;
    }
  }
}

// ---------------------------------------------------------------------------
// Flash attention: one block per (bt, h). 4 waves x 16 q-rows. 33 j-tiles of 64.
__global__ __launch_bounds__(256) void attn_kernel(const ushort* __restrict__ q,
                                                   const ushort* __restrict__ kv,
                                                   ushort* __restrict__ o) {
  const int blk = blockIdx.x;
  const int bt = blk >> 4;
  const int h = blk & 15;
  const int tid = threadIdx.x;
  const int wave = tid >> 6;
  const int lane = tid & 63;
  const int lr = lane & 15;
  const int lg = lane >> 4;

  __shared__ ushort vt[64][72];
  __shared__ ushort pl[4][16][72];

  const ushort* qbase = q + (size_t)(bt * 64 + wave * 16) * ADIM + h * HD;
  bf16x8 qf[2];
#pragma unroll
  for (int ks = 0; ks < 2; ++ks)
    qf[ks] = *(const bf16x8*)(qbase + (size_t)lr * ADIM + ks * 32 + lg * 8);

  const ushort* kvb = kv + (size_t)bt * NKV * 2048;

  f32x4 accO[4];
#pragma unroll
  for (int n = 0; n < 4; ++n) accO[n] = (f32x4){0.f, 0.f, 0.f, 0.f};
  float mrun[4] = {-1e30f, -1e30f, -1e30f, -1e30f};
  float lrun[4] = {0.f, 0.f, 0.f, 0.f};

  for (int jt = 0; jt < NKV / 64; ++jt) {
    const int j0 = jt * 64;
    __syncthreads();

    {
      int jj = tid >> 2;
      int dbase = (tid & 3) * 16;
#pragma unroll
      for (int half = 0; half < 2; ++half) {
        int d0 = dbase + half * 8;
        bf16x8 vv = *(const bf16x8*)(kvb + (size_t)(j0 + jj) * 2048 + ADIM + h * HD + d0);
#pragma unroll
        for (int e = 0; e < 8; ++e) vt[d0 + e][jj] = ((const ushort*)&vv)[e];
      }
    }

    f32x4 s[4];
#pragma unroll
    for (int nj = 0; nj < 4; ++nj) s[nj] = (f32x4){0.f, 0.f, 0.f, 0.f};
#pragma unroll
    for (int nj = 0; nj < 4; ++nj)
#pragma unroll
      for (int ks = 0; ks < 2; ++ks) {
        bf16x8 kf = *(const bf16x8*)(kvb + (size_t)(j0 + nj * 16 + lr) * 2048 +
                                     h * HD + ks * 32 + lg * 8);
        s[nj] = mfma16(qf[ks], kf, s[nj]);
      }

    float mt[4], corr[4], psum[4];
#pragma unroll
    for (int r = 0; r < 4; ++r)
      mt[r] = fmaxf(fmaxf(s[0][r], s[1][r]), fmaxf(s[2][r], s[3][r]));
#pragma unroll
    for (int off = 1; off < 16; off <<= 1)
#pragma unroll
      for (int r = 0; r < 4; ++r) mt[r] = fmaxf(mt[r], __shfl_xor(mt[r], off, 64));
#pragma unroll
    for (int r = 0; r < 4; ++r) {
      float mn = fmaxf(mrun[r], mt[r]);
      corr[r] = __expf(mrun[r] - mn);
      mrun[r] = mn;
      psum[r] = 0.f;
    }
#pragma unroll
    for (int nj = 0; nj < 4; ++nj)
#pragma unroll
      for (int r = 0; r < 4; ++r) {
        float pv = __expf(s[nj][r] - mrun[r]);
        s[nj][r] = pv;
        psum[r] += pv;
      }
#pragma unroll
    for (int off = 1; off < 16; off <<= 1)
#pragma unroll
      for (int r = 0; r < 4; ++r) psum[r] += __shfl_xor(psum[r], off, 64);
#pragma unroll
    for (int r = 0; r < 4; ++r) lrun[r] = lrun[r] * corr[r] + psum[r];
#pragma unroll
    for (int n = 0; n < 4; ++n)
#pragma unroll
      for (int r = 0; r < 4; ++r) accO[n][r] *= corr[r];

#pragma unroll
    for (int nj = 0; nj < 4; ++nj)
#pragma unroll
      for (int r = 0; r < 4; ++r)
        pl[wave][lg * 4 + r][nj * 16 + lr] = f2bf(s[nj][r]);
    __syncthreads();

    bf16x8 pf[2];
#pragma unroll
    for (int ks = 0; ks < 2; ++ks)
      pf[ks] = *(const bf16x8*)&pl[wave][lr][ks * 32 + lg * 8];
#pragma unroll
    for (int nd = 0; nd < 4; ++nd)
#pragma unroll
      for (int ks = 0; ks < 2; ++ks) {
        bf16x8 vf = *(const bf16x8*)&vt[nd * 16 + lr][ks * 32 + lg * 8];
        accO[nd] = mfma16(pf[ks], vf, accO[nd]);
      }
  }

#pragma unroll
  for (int nd = 0; nd < 4; ++nd)
#pragma unroll
    for (int r = 0; r < 4; ++r) {
      float vv = accO[nd][r] / lrun[r];
      int row = bt * 64 + wave * 16 + lg * 4 + r;
      o[(size_t)row * ADIM + h * HD + nd * 16 + lr] = f2bf(vv);
    }
}

// ---------------------------------------------------------------------------
extern "C" void kernel_launch(void* const* d_in, const int* in_sizes, int n_in,
                              void* d_out, int out_size, void* d_ws, size_t ws_size,
                              hipStream_t stream) {
  const float* latents = (const float*)d_in[0];
  const float* x = (const float*)d_in[1];
  const float* Wq = (const float*)d_in[2];
  const float* Wkv = (const float*)d_in[3];
  const float* Wout = (const float*)d_in[4];
  const float* bout = (const float*)d_in[5];
  const float* lnl_w = (const float*)d_in[6];
  const float* lnl_b = (const float*)d_in[7];
  const float* lnm_w = (const float*)d_in[8];
  const float* lnm_b = (const float*)d_in[9];

  char* ws = (char*)d_ws;
  size_t off = 0;
  auto alloc = [&](size_t bytes) -> void* {
    void* p = ws + off;
    off += (bytes + 255) & ~(size_t)255;
    return p;
  };
  ushort* kvin = (ushort*)alloc((size_t)BT * NKV * D_ * 2);
  ushort* kvo  = (ushort*)alloc((size_t)BT * NKV * 2048 * 2);
  ushort* qb   = (ushort*)alloc((size_t)BT * NLAT * ADIM * 2);
  ushort* ao   = (ushort*)alloc((size_t)BT * NLAT * ADIM * 2);
  ushort* WqT  = (ushort*)alloc((size_t)D_ * ADIM * 2);
  ushort* WkvT = (ushort*)alloc((size_t)D_ * 2 * ADIM * 2);
  ushort* WoutT = (ushort*)alloc((size_t)ADIM * D_ * 2);

  // 128 KB dynamic LDS for gemm256
  hipFuncSetAttribute((const void*)gemm256,
                      hipFuncAttributeMaxDynamicSharedMemorySize, 131072);

  // 1) weights -> bf16 B^T
  wtrans<<<dim3(ADIM / 64, D_ / 64), 256, 0, stream>>>(Wq, WqT, D_, ADIM);
  wtrans<<<dim3(2 * ADIM / 64, D_ / 64), 256, 0, stream>>>(Wkv, WkvT, D_, 2 * ADIM);
  wtrans<<<dim3(D_ / 64, ADIM / 64), 256, 0, stream>>>(Wout, WoutT, ADIM, D_);

  // 2) LN -> bf16 kv_in
  ln_kernel<<<BT * NKV, 256, 0, stream>>>(latents, x, lnl_w, lnl_b, lnm_w, lnm_b, kvin);

  // 3) q = lat_ln @ Wq (remapped A rows, 0.125 folded)
  gemm_bt<1, 1><<<dim3(ADIM / 128, BT * NLAT / 128), 256, 0, stream>>>(
      kvin, WqT, qb, nullptr, BT * NLAT, ADIM, D_, ADIM);

  // 4) kv = kv_in @ Wkv  — 256^2 ring pipeline + cross-phase ds_read overlap
  gemm256<<<dim3(MT2 * 8), 512, 131072, stream>>>(kvin, WkvT, kvo);

  // 5) attention
  attn_kernel<<<BT * HEADS, 256, 0, stream>>>(qb, kvo, ao);

  // 6) out = ao @ Wout + bout
  gemm_bt<0, 2><<<dim3(D_ / 128, BT * NLAT / 128), 256, 0, stream>>>(
      ao, WoutT, d_out, bout, BT * NLAT, D_, ADIM, D_);
}

// Round 6
// 593.267 us; speedup vs baseline: 1.0132x; 1.0056x over previous
//
#include <hip/hip_runtime.h>
#include <hip/hip_bf16.h>
#include <stdint.h>

// Problem constants
#define B_    8
#define T_    4
#define NLAT  64
#define NMED  2048
#define NKV   2112      // NMED + NLAT
#define D_    1024
#define HEADS 16
#define HD    64
#define ADIM  1024
#define BT    32        // B_*T_

typedef __attribute__((ext_vector_type(8))) short bf16x8;
typedef __attribute__((ext_vector_type(4))) float f32x4;

__device__ __forceinline__ ushort f2bf(float f) {
  union { float f; uint32_t u; } v; v.f = f;
  return (ushort)((v.u + 0x7fff + ((v.u >> 16) & 1)) >> 16);
}

__device__ __forceinline__ void gload_lds16(const void* g, void* l) {
  __builtin_amdgcn_global_load_lds(
      (const __attribute__((address_space(1))) void*)g,
      (__attribute__((address_space(3))) void*)l, 16, 0, 0);
}

__device__ __forceinline__ f32x4 mfma16(bf16x8 a, bf16x8 b, f32x4 c) {
  return __builtin_amdgcn_mfma_f32_16x16x32_bf16(a, b, c, 0, 0, 0);
}

// ---------------------------------------------------------------------------
// Weight transpose + f32->bf16: dst[n][k] = src[k][n].  src [K][Nm], 64x64 tiles.
__global__ __launch_bounds__(256) void wtrans(const float* __restrict__ src,
                                              ushort* __restrict__ dst,
                                              int K, int Nm) {
  __shared__ float t[64][65];
  const int tr = blockIdx.y, tc = blockIdx.x;
  const int c = threadIdx.x & 63;
  const int r4 = threadIdx.x >> 6;
#pragma unroll
  for (int rr = 0; rr < 16; ++rr) {
    int r = r4 + rr * 4;
    t[r][c] = src[(size_t)(tr * 64 + r) * Nm + tc * 64 + c];
  }
  __syncthreads();
#pragma unroll
  for (int rr = 0; rr < 16; ++rr) {
    int n = r4 + rr * 4;
    dst[(size_t)(tc * 64 + n) * K + tr * 64 + c] = f2bf(t[c][n]);
  }
}

// ---------------------------------------------------------------------------
// LayerNorm -> bf16, writing concatenated kv_in.
__global__ __launch_bounds__(256) void ln_kernel(
    const float* __restrict__ lat, const float* __restrict__ x,
    const float* __restrict__ lnl_w, const float* __restrict__ lnl_b,
    const float* __restrict__ lnm_w, const float* __restrict__ lnm_b,
    ushort* __restrict__ kvin) {
  const int row = blockIdx.x;
  const int bt = row / NKV;
  const int j = row - bt * NKV;
  const float* src;
  const float* w;
  const float* bb;
  if (j < NMED) {
    src = x + ((size_t)bt * NMED + j) * D_;
    w = lnm_w; bb = lnm_b;
  } else {
    src = lat + ((size_t)bt * NLAT + (j - NMED)) * D_;
    w = lnl_w; bb = lnl_b;
  }
  const int tid = threadIdx.x;
  float4 v = ((const float4*)src)[tid];
  float s = v.x + v.y + v.z + v.w;
  float s2 = v.x * v.x + v.y * v.y + v.z * v.z + v.w * v.w;
#pragma unroll
  for (int off = 1; off < 64; off <<= 1) {
    s += __shfl_xor(s, off, 64);
    s2 += __shfl_xor(s2, off, 64);
  }
  __shared__ float red[8];
  const int wave = tid >> 6;
  if ((tid & 63) == 0) { red[wave] = s; red[4 + wave] = s2; }
  __syncthreads();
  float S = red[0] + red[1] + red[2] + red[3];
  float S2 = red[4] + red[5] + red[6] + red[7];
  const float inv = 1.f / (float)D_;
  float mu = S * inv;
  float var = S2 * inv - mu * mu;
  float rs = rsqrtf(var + 1e-5f);
  float4 wv = ((const float4*)w)[tid];
  float4 bv = ((const float4*)bb)[tid];
  ushort4 ov;
  ov.x = f2bf((v.x - mu) * rs * wv.x + bv.x);
  ov.y = f2bf((v.y - mu) * rs * wv.y + bv.y);
  ov.z = f2bf((v.z - mu) * rs * wv.z + bv.z);
  ov.w = f2bf((v.w - mu) * rs * wv.w + bv.w);
  ((ushort4*)(kvin + (size_t)row * D_))[tid] = ov;
}

// ---------------------------------------------------------------------------
// Unified 128x128 GEMM (m97 2-barrier structure, 3 blocks/CU) with:
//  - chunk-XOR LDS swizzle both-sides (0-conflict pattern verified in R2-R5)
//  - swapped-operand MFMA -> lane owns one C row, 4 consecutive cols/frag
//  - vector epilogue (ushort4 / float4+bias)
//  - bijective XCD swizzle on a flat 1D grid (nwg % 8 == 0 for all uses)
// AMODE:  0 = direct rows; 1 = q-GEMM remap (row -> kvin[bt*2112+2048+local])
// OUTMODE:0 = bf16; 1 = bf16 * 0.125 (q scale); 2 = f32 + bias
template <int AMODE, int OUTMODE>
__global__ __launch_bounds__(256, 3) void gemm128(const ushort* __restrict__ A,
                                                  const ushort* __restrict__ Bt,
                                                  void* __restrict__ C,
                                                  const float* __restrict__ bias,
                                                  int ntx, int nwg, int K, int ldc) {
  __shared__ ushort lsA[128 * 32];
  __shared__ ushort lsB[128 * 32];
  const int tid = threadIdx.x;
  const int lane = tid & 63;
  const int wave = tid >> 6;
  const int lr = lane & 15;
  const int lg = lane >> 4;
  const int wr = (wave >> 1) * 64;
  const int wc = (wave & 1) * 64;

  // bijective XCD swizzle (requires nwg % 8 == 0)
  const int g = blockIdx.x;
  const int cpx = nwg >> 3;
  const int v = (g & 7) * cpx + (g >> 3);
  const int bx = v % ntx;
  const int by = v / ntx;
  const long brow = (long)by * 128;
  const int bcol = bx * 128;

  const int pcx = lg ^ ((lr >> 1) & 3);  // physical 16B-chunk for frag reads

  f32x4 acc[4][4];
#pragma unroll
  for (int m = 0; m < 4; ++m)
#pragma unroll
    for (int n = 0; n < 4; ++n) acc[m][n] = (f32x4){0.f, 0.f, 0.f, 0.f};

  // staging decode (both-sides swizzle): slot s -> row = s>>2,
  // logical chunk = (s&3) ^ ((s>>3)&3), LDS byte base = (s&~63)*16
  const int s0 = tid, s1 = 256 + tid;
  const int r0 = s0 >> 2, r1 = s1 >> 2;
  const int c0 = (s0 & 3) ^ ((s0 >> 3) & 3);
  const int c1 = (s1 & 3) ^ ((s1 >> 3) & 3);
  const int o0 = (s0 & ~63) * 16;
  const int o1 = (s1 & ~63) * 16;

  long arow0, arow1;
  if (AMODE == 1) {
    int g0 = (int)brow + r0, g1 = (int)brow + r1;
    arow0 = (long)(g0 >> 6) * NKV + NMED + (g0 & 63);
    arow1 = (long)(g1 >> 6) * NKV + NMED + (g1 & 63);
  } else {
    arow0 = brow + r0;
    arow1 = brow + r1;
  }
  const long browB0 = (long)(bcol + r0) * K;
  const long browB1 = (long)(bcol + r1) * K;

  for (int k0 = 0; k0 < K; k0 += 32) {
    gload_lds16(A + arow0 * (long)K + k0 + c0 * 8, (char*)lsA + o0);
    gload_lds16(A + arow1 * (long)K + k0 + c1 * 8, (char*)lsA + o1);
    gload_lds16(Bt + browB0 + k0 + c0 * 8, (char*)lsB + o0);
    gload_lds16(Bt + browB1 + k0 + c1 * 8, (char*)lsB + o1);
    __syncthreads();   // compiler drains vmcnt before barrier -> tile visible

    bf16x8 af[4], bf[4];
#pragma unroll
    for (int m = 0; m < 4; ++m)
      af[m] = *(const bf16x8*)((char*)lsA + (wr + m * 16 + lr) * 64 + pcx * 16);
#pragma unroll
    for (int n = 0; n < 4; ++n)
      bf[n] = *(const bf16x8*)((char*)lsB + (wc + n * 16 + lr) * 64 + pcx * 16);
#pragma unroll
    for (int m = 0; m < 4; ++m)
#pragma unroll
      for (int n = 0; n < 4; ++n)
        acc[m][n] = mfma16(bf[n], af[m], acc[m][n]);   // swapped operands
    __syncthreads();   // frag reads done before next-tile overwrite
  }

  // epilogue: lane owns C row = ...+lr; cols = ...+n*16+lg*4+{0..3}
#pragma unroll
  for (int m = 0; m < 4; ++m) {
    long row = brow + wr + m * 16 + lr;
#pragma unroll
    for (int n = 0; n < 4; ++n) {
      int coln = bcol + wc + n * 16 + lg * 4;
      long off = row * (long)ldc + coln;
      if (OUTMODE == 2) {
        float4 bv = *(const float4*)(bias + coln);
        float4 o;
        o.x = acc[m][n][0] + bv.x;
        o.y = acc[m][n][1] + bv.y;
        o.z = acc[m][n][2] + bv.z;
        o.w = acc[m][n][3] + bv.w;
        *(float4*)((float*)C + off) = o;
      } else {
        const float sc = (OUTMODE == 1) ? 0.125f : 1.f;
        ushort4 o;
        o.x = f2bf(acc[m][n][0] * sc);
        o.y = f2bf(acc[m][n][1] * sc);
        o.z = f2bf(acc[m][n][2] * sc);
        o.w = f2bf(acc[m][n][3] * sc);
        *(ushort4*)((ushort*)C + off) = o;
      }
    }
  }
}

// ---------------------------------------------------------------------------
// Flash attention: one block per (bt, h). 4 waves x 16 q-rows. 33 j-tiles of 64.
// NEW: K tile staged once into XOR-swizzled LDS (vector writes) instead of
// 4x-redundant per-wave global frag reads.
__global__ __launch_bounds__(256) void attn_kernel(const ushort* __restrict__ q,
                                                   const ushort* __restrict__ kv,
                                                   ushort* __restrict__ o) {
  const int blk = blockIdx.x;
  const int bt = blk >> 4;
  const int h = blk & 15;
  const int tid = threadIdx.x;
  const int wave = tid >> 6;
  const int lane = tid & 63;
  const int lr = lane & 15;
  const int lg = lane >> 4;

  __shared__ ushort vt[64][72];      // V^T tile (padded)
  __shared__ ushort pl[4][16][72];   // per-wave P tile (padded)
  __shared__ ushort kl[64 * 64];     // K tile, linear rows of 128B, slot-XOR

  const ushort* qbase = q + (size_t)(bt * 64 + wave * 16) * ADIM + h * HD;
  bf16x8 qf[2];
#pragma unroll
  for (int ks = 0; ks < 2; ++ks)
    qf[ks] = *(const bf16x8*)(qbase + (size_t)lr * ADIM + ks * 32 + lg * 8);

  const ushort* kvb = kv + (size_t)bt * NKV * 2048;

  f32x4 accO[4];
#pragma unroll
  for (int n = 0; n < 4; ++n) accO[n] = (f32x4){0.f, 0.f, 0.f, 0.f};
  float mrun[4] = {-1e30f, -1e30f, -1e30f, -1e30f};
  float lrun[4] = {0.f, 0.f, 0.f, 0.f};

  for (int jt = 0; jt < NKV / 64; ++jt) {
    const int j0 = jt * 64;
    __syncthreads();   // prev tile's kl/vt/pl reads all done

    // Stage K tile: kl[j][d], vector writes, slot-XOR swizzle.
    // thread t: j = t>>2, d0 = (t&3)*16; slots d0/8, d0/8+1; phys = slot^(j&7)
    {
      const int j = tid >> 2;
      const int q4 = tid & 3;
      const ushort* src = kvb + (size_t)(j0 + j) * 2048 + h * HD + q4 * 16;
#pragma unroll
      for (int half = 0; half < 2; ++half) {
        bf16x8 k8 = *(const bf16x8*)(src + half * 8);
        int phys = (q4 * 2 + half) ^ (j & 7);
        *(bf16x8*)((char*)kl + j * 128 + phys * 16) = k8;
      }
    }

    // Stage V^T: vt[d][j] = v[j0+j][h*64+d]
    {
      int jj = tid >> 2;
      int dbase = (tid & 3) * 16;
#pragma unroll
      for (int half = 0; half < 2; ++half) {
        int d0 = dbase + half * 8;
        bf16x8 vv = *(const bf16x8*)(kvb + (size_t)(j0 + jj) * 2048 + ADIM + h * HD + d0);
#pragma unroll
        for (int e = 0; e < 8; ++e) vt[d0 + e][jj] = ((const ushort*)&vv)[e];
      }
    }
    __syncthreads();   // kl + vt visible

    // S = q @ k^T  (K frags from swizzled LDS)
    f32x4 s[4];
#pragma unroll
    for (int nj = 0; nj < 4; ++nj) s[nj] = (f32x4){0.f, 0.f, 0.f, 0.f};
#pragma unroll
    for (int nj = 0; nj < 4; ++nj)
#pragma unroll
      for (int ks = 0; ks < 2; ++ks) {
        int row = nj * 16 + lr;
        int phys = (4 * ks + lg) ^ (lr & 7);
        bf16x8 kf = *(const bf16x8*)((char*)kl + row * 128 + phys * 16);
        s[nj] = mfma16(qf[ks], kf, s[nj]);
      }

    // Online softmax over this wave's 16 rows (row = 4*lg + r)
    float mt[4], corr[4], psum[4];
#pragma unroll
    for (int r = 0; r < 4; ++r)
      mt[r] = fmaxf(fmaxf(s[0][r], s[1][r]), fmaxf(s[2][r], s[3][r]));
#pragma unroll
    for (int off = 1; off < 16; off <<= 1)
#pragma unroll
      for (int r = 0; r < 4; ++r) mt[r] = fmaxf(mt[r], __shfl_xor(mt[r], off, 64));
#pragma unroll
    for (int r = 0; r < 4; ++r) {
      float mn = fmaxf(mrun[r], mt[r]);
      corr[r] = __expf(mrun[r] - mn);
      mrun[r] = mn;
      psum[r] = 0.f;
    }
#pragma unroll
    for (int nj = 0; nj < 4; ++nj)
#pragma unroll
      for (int r = 0; r < 4; ++r) {
        float pv = __expf(s[nj][r] - mrun[r]);
        s[nj][r] = pv;
        psum[r] += pv;
      }
#pragma unroll
    for (int off = 1; off < 16; off <<= 1)
#pragma unroll
      for (int r = 0; r < 4; ++r) psum[r] += __shfl_xor(psum[r], off, 64);
#pragma unroll
    for (int r = 0; r < 4; ++r) lrun[r] = lrun[r] * corr[r] + psum[r];
#pragma unroll
    for (int n = 0; n < 4; ++n)
#pragma unroll
      for (int r = 0; r < 4; ++r) accO[n][r] *= corr[r];

    // P -> LDS (per-wave region), then PV
#pragma unroll
    for (int nj = 0; nj < 4; ++nj)
#pragma unroll
      for (int r = 0; r < 4; ++r)
        pl[wave][lg * 4 + r][nj * 16 + lr] = f2bf(s[nj][r]);
    __syncthreads();   // pl visible

    bf16x8 pf[2];
#pragma unroll
    for (int ks = 0; ks < 2; ++ks)
      pf[ks] = *(const bf16x8*)&pl[wave][lr][ks * 32 + lg * 8];
#pragma unroll
    for (int nd = 0; nd < 4; ++nd)
#pragma unroll
      for (int ks = 0; ks < 2; ++ks) {
        bf16x8 vf = *(const bf16x8*)&vt[nd * 16 + lr][ks * 32 + lg * 8];
        accO[nd] = mfma16(pf[ks], vf, accO[nd]);
      }
  }

  // O = accO / l
#pragma unroll
  for (int nd = 0; nd < 4; ++nd)
#pragma unroll
    for (int r = 0; r < 4; ++r) {
      float vv = accO[nd][r] / lrun[r];
      int row = bt * 64 + wave * 16 + lg * 4 + r;
      o[(size_t)row * ADIM + h * HD + nd * 16 + lr] = f2bf(vv);
    }
}

// ---------------------------------------------------------------------------
extern "C" void kernel_launch(void* const* d_in, const int* in_sizes, int n_in,
                              void* d_out, int out_size, void* d_ws, size_t ws_size,
                              hipStream_t stream) {
  const float* latents = (const float*)d_in[0];
  const float* x = (const float*)d_in[1];
  const float* Wq = (const float*)d_in[2];
  const float* Wkv = (const float*)d_in[3];
  const float* Wout = (const float*)d_in[4];
  const float* bout = (const float*)d_in[5];
  const float* lnl_w = (const float*)d_in[6];
  const float* lnl_b = (const float*)d_in[7];
  const float* lnm_w = (const float*)d_in[8];
  const float* lnm_b = (const float*)d_in[9];

  char* ws = (char*)d_ws;
  size_t off = 0;
  auto alloc = [&](size_t bytes) -> void* {
    void* p = ws + off;
    off += (bytes + 255) & ~(size_t)255;
    return p;
  };
  ushort* kvin = (ushort*)alloc((size_t)BT * NKV * D_ * 2);
  ushort* kvo  = (ushort*)alloc((size_t)BT * NKV * 2048 * 2);
  ushort* qb   = (ushort*)alloc((size_t)BT * NLAT * ADIM * 2);
  ushort* ao   = (ushort*)alloc((size_t)BT * NLAT * ADIM * 2);
  ushort* WqT  = (ushort*)alloc((size_t)D_ * ADIM * 2);
  ushort* WkvT = (ushort*)alloc((size_t)D_ * 2 * ADIM * 2);
  ushort* WoutT = (ushort*)alloc((size_t)ADIM * D_ * 2);

  // 1) weights -> bf16 B^T
  wtrans<<<dim3(ADIM / 64, D_ / 64), 256, 0, stream>>>(Wq, WqT, D_, ADIM);
  wtrans<<<dim3(2 * ADIM / 64, D_ / 64), 256, 0, stream>>>(Wkv, WkvT, D_, 2 * ADIM);
  wtrans<<<dim3(D_ / 64, ADIM / 64), 256, 0, stream>>>(Wout, WoutT, ADIM, D_);

  // 2) LN -> bf16 kv_in
  ln_kernel<<<BT * NKV, 256, 0, stream>>>(latents, x, lnl_w, lnl_b, lnm_w, lnm_b, kvin);

  // 3) q = lat_ln @ Wq (remapped A rows, 0.125 folded)   nwg = 8*16 = 128
  gemm128<1, 1><<<dim3(128), 256, 0, stream>>>(
      kvin, WqT, qb, nullptr, ADIM / 128, 128, D_, ADIM);

  // 4) kv = kv_in @ Wkv   nwg = 16 * 528 = 8448
  gemm128<0, 0><<<dim3(8448), 256, 0, stream>>>(
      kvin, WkvT, kvo, nullptr, 2048 / 128, 8448, D_, 2048);

  // 5) attention
  attn_kernel<<<BT * HEADS, 256, 0, stream>>>(qb, kvo, ao);

  // 6) out = ao @ Wout + bout   nwg = 8*16 = 128
  gemm128<0, 2><<<dim3(128), 256, 0, stream>>>(
      ao, WoutT, d_out, bout, D_ / 128, 128, ADIM, D_);
}

// Round 7
// 555.513 us; speedup vs baseline: 1.0821x; 1.0680x over previous
//
#include <hip/hip_runtime.h>
#include <hip/hip_bf16.h>
#include <stdint.h>

// Problem constants
#define B_    8
#define T_    4
#define NLAT  64
#define NMED  2048
#define NKV   2112      // NMED + NLAT
#define D_    1024
#define HEADS 16
#define HD    64
#define ADIM  1024
#define BT    32        // B_*T_

#define GK    1024      // kv-GEMM K
#define GN    2048      // kv-GEMM N
#define GM    67584     // BT*NKV
#define MT2   264       // GM/256
#define NSLC  32        // GK/32

typedef __attribute__((ext_vector_type(8))) short bf16x8;
typedef __attribute__((ext_vector_type(4))) float f32x4;

__device__ __forceinline__ ushort f2bf(float f) {
  union { float f; uint32_t u; } v; v.f = f;
  return (ushort)((v.u + 0x7fff + ((v.u >> 16) & 1)) >> 16);
}

__device__ __forceinline__ void gload_lds16(const void* g, void* l) {
  __builtin_amdgcn_global_load_lds(
      (const __attribute__((address_space(1))) void*)g,
      (__attribute__((address_space(3))) void*)l, 16, 0, 0);
}

__device__ __forceinline__ f32x4 mfma16(bf16x8 a, bf16x8 b, f32x4 c) {
  return __builtin_amdgcn_mfma_f32_16x16x32_bf16(a, b, c, 0, 0, 0);
}

// ---------------------------------------------------------------------------
// Weight transpose + f32->bf16: dst[n][k] = src[k][n].  src [K][Nm], 64x64 tiles.
__global__ __launch_bounds__(256) void wtrans(const float* __restrict__ src,
                                              ushort* __restrict__ dst,
                                              int K, int Nm) {
  __shared__ float t[64][65];
  const int tr = blockIdx.y, tc = blockIdx.x;
  const int c = threadIdx.x & 63;
  const int r4 = threadIdx.x >> 6;
#pragma unroll
  for (int rr = 0; rr < 16; ++rr) {
    int r = r4 + rr * 4;
    t[r][c] = src[(size_t)(tr * 64 + r) * Nm + tc * 64 + c];
  }
  __syncthreads();
#pragma unroll
  for (int rr = 0; rr < 16; ++rr) {
    int n = r4 + rr * 4;
    dst[(size_t)(tc * 64 + n) * K + tr * 64 + c] = f2bf(t[c][n]);
  }
}

// ---------------------------------------------------------------------------
// LayerNorm -> bf16, writing concatenated kv_in.
__global__ __launch_bounds__(256) void ln_kernel(
    const float* __restrict__ lat, const float* __restrict__ x,
    const float* __restrict__ lnl_w, const float* __restrict__ lnl_b,
    const float* __restrict__ lnm_w, const float* __restrict__ lnm_b,
    ushort* __restrict__ kvin) {
  const int row = blockIdx.x;
  const int bt = row / NKV;
  const int j = row - bt * NKV;
  const float* src;
  const float* w;
  const float* bb;
  if (j < NMED) {
    src = x + ((size_t)bt * NMED + j) * D_;
    w = lnm_w; bb = lnm_b;
  } else {
    src = lat + ((size_t)bt * NLAT + (j - NMED)) * D_;
    w = lnl_w; bb = lnl_b;
  }
  const int tid = threadIdx.x;
  float4 v = ((const float4*)src)[tid];
  float s = v.x + v.y + v.z + v.w;
  float s2 = v.x * v.x + v.y * v.y + v.z * v.z + v.w * v.w;
#pragma unroll
  for (int off = 1; off < 64; off <<= 1) {
    s += __shfl_xor(s, off, 64);
    s2 += __shfl_xor(s2, off, 64);
  }
  __shared__ float red[8];
  const int wave = tid >> 6;
  if ((tid & 63) == 0) { red[wave] = s; red[4 + wave] = s2; }
  __syncthreads();
  float S = red[0] + red[1] + red[2] + red[3];
  float S2 = red[4] + red[5] + red[6] + red[7];
  const float inv = 1.f / (float)D_;
  float mu = S * inv;
  float var = S2 * inv - mu * mu;
  float rs = rsqrtf(var + 1e-5f);
  float4 wv = ((const float4*)w)[tid];
  float4 bv = ((const float4*)bb)[tid];
  ushort4 ov;
  ov.x = f2bf((v.x - mu) * rs * wv.x + bv.x);
  ov.y = f2bf((v.y - mu) * rs * wv.y + bv.y);
  ov.z = f2bf((v.z - mu) * rs * wv.z + bv.z);
  ov.w = f2bf((v.w - mu) * rs * wv.w + bv.w);
  ((ushort4*)(kvin + (size_t)row * D_))[tid] = ov;
}

// ---------------------------------------------------------------------------
// 128x128 GEMM (m97 2-barrier structure, 3 blocks/CU) — small GEMMs only.
// AMODE:  0 = direct rows; 1 = q-GEMM remap (row -> kvin[bt*2112+2048+local])
// OUTMODE:1 = bf16 * 0.125 (q scale); 2 = f32 + bias
template <int AMODE, int OUTMODE>
__global__ __launch_bounds__(256, 3) void gemm128(const ushort* __restrict__ A,
                                                  const ushort* __restrict__ Bt,
                                                  void* __restrict__ C,
                                                  const float* __restrict__ bias,
                                                  int ntx, int nwg, int K, int ldc) {
  __shared__ ushort lsA[128 * 32];
  __shared__ ushort lsB[128 * 32];
  const int tid = threadIdx.x;
  const int lane = tid & 63;
  const int wave = tid >> 6;
  const int lr = lane & 15;
  const int lg = lane >> 4;
  const int wr = (wave >> 1) * 64;
  const int wc = (wave & 1) * 64;

  const int g = blockIdx.x;
  const int cpx = nwg >> 3;
  const int v = (g & 7) * cpx + (g >> 3);
  const int bx = v % ntx;
  const int by = v / ntx;
  const long brow = (long)by * 128;
  const int bcol = bx * 128;

  const int pcx = lg ^ ((lr >> 1) & 3);

  f32x4 acc[4][4];
#pragma unroll
  for (int m = 0; m < 4; ++m)
#pragma unroll
    for (int n = 0; n < 4; ++n) acc[m][n] = (f32x4){0.f, 0.f, 0.f, 0.f};

  const int s0 = tid, s1 = 256 + tid;
  const int r0 = s0 >> 2, r1 = s1 >> 2;
  const int c0 = (s0 & 3) ^ ((s0 >> 3) & 3);
  const int c1 = (s1 & 3) ^ ((s1 >> 3) & 3);
  const int o0 = (s0 & ~63) * 16;
  const int o1 = (s1 & ~63) * 16;

  long arow0, arow1;
  if (AMODE == 1) {
    int g0 = (int)brow + r0, g1 = (int)brow + r1;
    arow0 = (long)(g0 >> 6) * NKV + NMED + (g0 & 63);
    arow1 = (long)(g1 >> 6) * NKV + NMED + (g1 & 63);
  } else {
    arow0 = brow + r0;
    arow1 = brow + r1;
  }
  const long browB0 = (long)(bcol + r0) * K;
  const long browB1 = (long)(bcol + r1) * K;

  for (int k0 = 0; k0 < K; k0 += 32) {
    gload_lds16(A + arow0 * (long)K + k0 + c0 * 8, (char*)lsA + o0);
    gload_lds16(A + arow1 * (long)K + k0 + c1 * 8, (char*)lsA + o1);
    gload_lds16(Bt + browB0 + k0 + c0 * 8, (char*)lsB + o0);
    gload_lds16(Bt + browB1 + k0 + c1 * 8, (char*)lsB + o1);
    __syncthreads();

    bf16x8 af[4], bf[4];
#pragma unroll
    for (int m = 0; m < 4; ++m)
      af[m] = *(const bf16x8*)((char*)lsA + (wr + m * 16 + lr) * 64 + pcx * 16);
#pragma unroll
    for (int n = 0; n < 4; ++n)
      bf[n] = *(const bf16x8*)((char*)lsB + (wc + n * 16 + lr) * 64 + pcx * 16);
#pragma unroll
    for (int m = 0; m < 4; ++m)
#pragma unroll
      for (int n = 0; n < 4; ++n)
        acc[m][n] = mfma16(bf[n], af[m], acc[m][n]);
    __syncthreads();
  }

#pragma unroll
  for (int m = 0; m < 4; ++m) {
    long row = brow + wr + m * 16 + lr;
#pragma unroll
    for (int n = 0; n < 4; ++n) {
      int coln = bcol + wc + n * 16 + lg * 4;
      long off = row * (long)ldc + coln;
      if (OUTMODE == 2) {
        float4 bv = *(const float4*)(bias + coln);
        float4 o;
        o.x = acc[m][n][0] + bv.x;
        o.y = acc[m][n][1] + bv.y;
        o.z = acc[m][n][2] + bv.z;
        o.w = acc[m][n][3] + bv.w;
        *(float4*)((float*)C + off) = o;
      } else {
        const float sc = (OUTMODE == 1) ? 0.125f : 1.f;
        ushort4 o;
        o.x = f2bf(acc[m][n][0] * sc);
        o.y = f2bf(acc[m][n][1] * sc);
        o.z = f2bf(acc[m][n][2] * sc);
        o.w = f2bf(acc[m][n][3] * sc);
        *(ushort4*)((ushort*)C + off) = o;
      }
    }
  }
}

// ---------------------------------------------------------------------------
// kv-GEMM: 256x256 tile, 8 waves of 128x64 (2M x 4N), BK=32, 4-slot LDS ring
// (128 KB), stage-ahead 3, vmcnt(8) per slice, cross-phase ds_read pipelining
// with counted lgkmcnt(4/8).  (R5 version — best measured: 346 us.)
__global__ __launch_bounds__(512, 2) void gemm256(const ushort* __restrict__ A,
                                                  const ushort* __restrict__ Bt,
                                                  ushort* __restrict__ C) {
  extern __shared__ __align__(16) char smem[];  // 4 slots x (16KB A + 16KB B)
  const int tid = threadIdx.x;
  const int lane = tid & 63;
  const int wv = tid >> 6;
  const int wm = wv >> 2;
  const int wn = wv & 3;
  const int lr = lane & 15;
  const int lg = lane >> 4;

  const int g = blockIdx.x;
  const int v = (g & 7) * MT2 + (g >> 3);
  const int bx = v & 7;
  const int by = v >> 3;
  const long brow = (long)by * 256;
  const int bcol = bx * 256;

  const int pcx = lg ^ ((lr >> 1) & 3);
  const int rbA = wm * 128 + lr;
  const int rbB = wn * 64 + lr;

  f32x4 acc[8][4];
#pragma unroll
  for (int m = 0; m < 8; ++m)
#pragma unroll
    for (int n = 0; n < 4; ++n) acc[m][n] = (f32x4){0.f, 0.f, 0.f, 0.f};

  const int s0 = tid, s1 = 512 + tid;
  const int r0 = s0 >> 2, r1 = s1 >> 2;
  const int c0 = (s0 & 3) ^ ((s0 >> 3) & 3);
  const int c1 = (s1 & 3) ^ ((s1 >> 3) & 3);
  const int o0 = (s0 & ~63) * 16;
  const int o1 = (s1 & ~63) * 16;

#define STAGE_A(slc, slot)                                                     \
  {                                                                            \
    long k0 = (long)(slc) * 32;                                                \
    char* db = smem + (slot) * 32768;                                          \
    gload_lds16(A + (brow + r0) * (long)GK + k0 + c0 * 8, db + o0);            \
    gload_lds16(A + (brow + r1) * (long)GK + k0 + c1 * 8, db + o1);            \
  }
#define STAGE_B(slc, slot)                                                     \
  {                                                                            \
    long k0 = (long)(slc) * 32;                                                \
    char* db = smem + (slot) * 32768 + 16384;                                  \
    gload_lds16(Bt + (long)(bcol + r0) * GK + k0 + c0 * 8, db + o0);           \
    gload_lds16(Bt + (long)(bcol + r1) * GK + k0 + c1 * 8, db + o1);           \
  }

  bf16x8 a0[4], a1[4], b0[4], b1[4];

  STAGE_A(0, 0); STAGE_B(0, 0);
  STAGE_A(1, 1); STAGE_B(1, 1);
  STAGE_A(2, 2); STAGE_B(2, 2);
  asm volatile("s_waitcnt vmcnt(8)" ::: "memory");
  __builtin_amdgcn_s_barrier();
#pragma unroll
  for (int m = 0; m < 4; ++m)
    a0[m] = *(const bf16x8*)(smem + (rbA + m * 16) * 64 + pcx * 16);
#pragma unroll
  for (int n = 0; n < 4; ++n)
    b0[n] = *(const bf16x8*)(smem + 16384 + (rbB + n * 16) * 64 + pcx * 16);
  __builtin_amdgcn_sched_barrier(0);

#define SLICE(T, BCUR, BNXT)                                                   \
  {                                                                            \
    const int t_ = (T);                                                        \
    const char* sA_ = smem + (t_ & 3) * 32768;                                 \
    const int ts_ = (t_ + 3 < NSLC) ? t_ + 3 : t_;                             \
    const int ws_ = (t_ + 3) & 3;                                              \
    /* ---- phase 0 ---- */                                                    \
    _Pragma("unroll")                                                          \
    for (int m = 0; m < 4; ++m)                                                \
      a1[m] = *(const bf16x8*)(sA_ + (rbA + (m + 4) * 16) * 64 + pcx * 16);    \
    STAGE_A(ts_, ws_);                                                         \
    __builtin_amdgcn_sched_barrier(0);                                         \
    __builtin_amdgcn_s_barrier();                                              \
    asm volatile("s_waitcnt lgkmcnt(4)" ::: "memory");                         \
    __builtin_amdgcn_sched_barrier(0);                                         \
    __builtin_amdgcn_s_setprio(1);                                             \
    _Pragma("unroll")                                                          \
    for (int m = 0; m < 4; ++m)                                                \
      _Pragma("unroll")                                                        \
      for (int n = 0; n < 4; ++n)                                              \
        acc[m][n] = mfma16(BCUR[n], a0[m], acc[m][n]);                         \
    __builtin_amdgcn_s_setprio(0);                                             \
    __builtin_amdgcn_sched_barrier(0);                                         \
    __builtin_amdgcn_s_barrier();                                              \
    /* ---- phase 1 ---- */                                                    \
    STAGE_B(ts_, ws_);                                                         \
    asm volatile("s_waitcnt vmcnt(8)" ::: "memory");                           \
    __builtin_amdgcn_sched_barrier(0);                                         \
    __builtin_amdgcn_s_barrier();                                              \
    {                                                                          \
      const int tn_ = (t_ + 1 < NSLC) ? t_ + 1 : t_;                           \
      const char* nA_ = smem + (tn_ & 3) * 32768;                              \
      const char* nB_ = nA_ + 16384;                                           \
      _Pragma("unroll")                                                        \
      for (int m = 0; m < 4; ++m)                                              \
        a0[m] = *(const bf16x8*)(nA_ + (rbA + m * 16) * 64 + pcx * 16);        \
      _Pragma("unroll")                                                        \
      for (int n = 0; n < 4; ++n)                                              \
        BNXT[n] = *(const bf16x8*)(nB_ + (rbB + n * 16) * 64 + pcx * 16);      \
    }                                                                          \
    __builtin_amdgcn_sched_barrier(0);                                         \
    asm volatile("s_waitcnt lgkmcnt(8)" ::: "memory");                         \
    __builtin_amdgcn_sched_barrier(0);                                         \
    __builtin_amdgcn_s_setprio(1);                                             \
    _Pragma("unroll")                                                          \
    for (int m = 0; m < 4; ++m)                                                \
      _Pragma("unroll")                                                        \
      for (int n = 0; n < 4; ++n)                                              \
        acc[m + 4][n] = mfma16(BCUR[n], a1[m], acc[m + 4][n]);                 \
    __builtin_amdgcn_s_setprio(0);                                             \
    __builtin_amdgcn_sched_barrier(0);                                         \
    __builtin_amdgcn_s_barrier();                                              \
  }

  for (int t = 0; t < NSLC; t += 2) {
    SLICE(t, b0, b1);
    SLICE(t + 1, b1, b0);
  }
#undef SLICE
#undef STAGE_A
#undef STAGE_B

#pragma unroll
  for (int m = 0; m < 8; ++m) {
    long row = brow + wm * 128 + m * 16 + lr;
    ushort* crow = C + row * GN + bcol + wn * 64 + lg * 4;
#pragma unroll
    for (int n = 0; n < 4; ++n) {
      ushort4 o;
      o.x = f2bf(acc[m][n][0]);
      o.y = f2bf(acc[m][n][1]);
      o.z = f2bf(acc[m][n][2]);
      o.w = f2bf(acc[m][n][3]);
      *(ushort4*)(crow + n * 16) = o;
    }
  }
}

// ---------------------------------------------------------------------------
// Flash attention: one block per (bt, h). 4 waves x 16 q-rows. 33 j-tiles of 64.
// K tile staged in XOR-swizzled LDS; NEW: register double-buffered K/V global
// loads (T14 async-stage) — tile t+1's 4x16B loads issue before tile t's
// compute, hiding ~900cy HBM latency under QK^T+softmax+PV.
__global__ __launch_bounds__(256) void attn_kernel(const ushort* __restrict__ q,
                                                   const ushort* __restrict__ kv,
                                                   ushort* __restrict__ o) {
  const int blk = blockIdx.x;
  const int bt = blk >> 4;
  const int h = blk & 15;
  const int tid = threadIdx.x;
  const int wave = tid >> 6;
  const int lane = tid & 63;
  const int lr = lane & 15;
  const int lg = lane >> 4;

  __shared__ ushort vt[64][72];      // V^T tile (padded)
  __shared__ ushort pl[4][16][72];   // per-wave P tile (padded)
  __shared__ ushort kl[64 * 64];     // K tile, rows of 128B, slot-XOR swizzle

  const ushort* qbase = q + (size_t)(bt * 64 + wave * 16) * ADIM + h * HD;
  bf16x8 qf[2];
#pragma unroll
  for (int ks = 0; ks < 2; ++ks)
    qf[ks] = *(const bf16x8*)(qbase + (size_t)lr * ADIM + ks * 32 + lg * 8);

  const ushort* kvb = kv + (size_t)bt * NKV * 2048;
  const int jj = tid >> 2;       // row within tile this thread stages
  const int q4 = tid & 3;        // 16-elem chunk

  f32x4 accO[4];
#pragma unroll
  for (int n = 0; n < 4; ++n) accO[n] = (f32x4){0.f, 0.f, 0.f, 0.f};
  float mrun[4] = {-1e30f, -1e30f, -1e30f, -1e30f};
  float lrun[4] = {0.f, 0.f, 0.f, 0.f};

  // prefetch tile 0 into regs
  bf16x8 kr0, kr1, vr0, vr1;
  {
    const ushort* src = kvb + (size_t)jj * 2048 + h * HD + q4 * 16;
    kr0 = *(const bf16x8*)(src);
    kr1 = *(const bf16x8*)(src + 8);
    vr0 = *(const bf16x8*)(src + ADIM);
    vr1 = *(const bf16x8*)(src + ADIM + 8);
  }

  for (int jt = 0; jt < NKV / 64; ++jt) {
    __syncthreads();   // prev tile's kl/vt/pl reads all done

    // write staged regs -> LDS (compiler waits the loads' vmcnt here)
    {
      int p0 = (q4 * 2) ^ (jj & 7);
      int p1 = (q4 * 2 + 1) ^ (jj & 7);
      *(bf16x8*)((char*)kl + jj * 128 + p0 * 16) = kr0;
      *(bf16x8*)((char*)kl + jj * 128 + p1 * 16) = kr1;
      int d0 = q4 * 16;
#pragma unroll
      for (int e = 0; e < 8; ++e) {
        vt[d0 + e][jj] = ((const ushort*)&vr0)[e];
        vt[d0 + 8 + e][jj] = ((const ushort*)&vr1)[e];
      }
    }

    // issue next tile's loads (fly under this tile's compute)
    bf16x8 nk0, nk1, nv0, nv1;
    {
      const int tn = (jt + 1 < NKV / 64) ? jt + 1 : jt;  // dummy at tail
      const ushort* src = kvb + (size_t)(tn * 64 + jj) * 2048 + h * HD + q4 * 16;
      nk0 = *(const bf16x8*)(src);
      nk1 = *(const bf16x8*)(src + 8);
      nv0 = *(const bf16x8*)(src + ADIM);
      nv1 = *(const bf16x8*)(src + ADIM + 8);
    }
    __syncthreads();   // kl + vt visible

    // S = q @ k^T  (K frags from swizzled LDS)
    f32x4 s[4];
#pragma unroll
    for (int nj = 0; nj < 4; ++nj) s[nj] = (f32x4){0.f, 0.f, 0.f, 0.f};
#pragma unroll
    for (int nj = 0; nj < 4; ++nj)
#pragma unroll
      for (int ks = 0; ks < 2; ++ks) {
        int row = nj * 16 + lr;
        int phys = (4 * ks + lg) ^ (lr & 7);
        bf16x8 kf = *(const bf16x8*)((char*)kl + row * 128 + phys * 16);
        s[nj] = mfma16(qf[ks], kf, s[nj]);
      }

    // Online softmax over this wave's 16 rows (row = 4*lg + r)
    float mt[4], corr[4], psum[4];
#pragma unroll
    for (int r = 0; r < 4; ++r)
      mt[r] = fmaxf(fmaxf(s[0][r], s[1][r]), fmaxf(s[2][r], s[3][r]));
#pragma unroll
    for (int off = 1; off < 16; off <<= 1)
#pragma unroll
      for (int r = 0; r < 4; ++r) mt[r] = fmaxf(mt[r], __shfl_xor(mt[r], off, 64));
#pragma unroll
    for (int r = 0; r < 4; ++r) {
      float mn = fmaxf(mrun[r], mt[r]);
      corr[r] = __expf(mrun[r] - mn);
      mrun[r] = mn;
      psum[r] = 0.f;
    }
#pragma unroll
    for (int nj = 0; nj < 4; ++nj)
#pragma unroll
      for (int r = 0; r < 4; ++r) {
        float pv = __expf(s[nj][r] - mrun[r]);
        s[nj][r] = pv;
        psum[r] += pv;
      }
#pragma unroll
    for (int off = 1; off < 16; off <<= 1)
#pragma unroll
      for (int r = 0; r < 4; ++r) psum[r] += __shfl_xor(psum[r], off, 64);
#pragma unroll
    for (int r = 0; r < 4; ++r) lrun[r] = lrun[r] * corr[r] + psum[r];
#pragma unroll
    for (int n = 0; n < 4; ++n)
#pragma unroll
      for (int r = 0; r < 4; ++r) accO[n][r] *= corr[r];

    // P -> LDS (per-wave region), then PV
#pragma unroll
    for (int nj = 0; nj < 4; ++nj)
#pragma unroll
      for (int r = 0; r < 4; ++r)
        pl[wave][lg * 4 + r][nj * 16 + lr] = f2bf(s[nj][r]);
    __syncthreads();   // pl visible

    bf16x8 pf[2];
#pragma unroll
    for (int ks = 0; ks < 2; ++ks)
      pf[ks] = *(const bf16x8*)&pl[wave][lr][ks * 32 + lg * 8];
#pragma unroll
    for (int nd = 0; nd < 4; ++nd)
#pragma unroll
      for (int ks = 0; ks < 2; ++ks) {
        bf16x8 vf = *(const bf16x8*)&vt[nd * 16 + lr][ks * 32 + lg * 8];
        accO[nd] = mfma16(pf[ks], vf, accO[nd]);
      }

    // rotate prefetch regs
    kr0 = nk0; kr1 = nk1; vr0 = nv0; vr1 = nv1;
  }

  // O = accO / l
#pragma unroll
  for (int nd = 0; nd < 4; ++nd)
#pragma unroll
    for (int r = 0; r < 4; ++r) {
      float vv = accO[nd][r] / lrun[r];
      int row = bt * 64 + wave * 16 + lg * 4 + r;
      o[(size_t)row * ADIM + h * HD + nd * 16 + lr] = f2bf(vv);
    }
}

// ---------------------------------------------------------------------------
extern "C" void kernel_launch(void* const* d_in, const int* in_sizes, int n_in,
                              void* d_out, int out_size, void* d_ws, size_t ws_size,
                              hipStream_t stream) {
  const float* latents = (const float*)d_in[0];
  const float* x = (const float*)d_in[1];
  const float* Wq = (const float*)d_in[2];
  const float* Wkv = (const float*)d_in[3];
  const float* Wout = (const float*)d_in[4];
  const float* bout = (const float*)d_in[5];
  const float* lnl_w = (const float*)d_in[6];
  const float* lnl_b = (const float*)d_in[7];
  const float* lnm_w = (const float*)d_in[8];
  const float* lnm_b = (const float*)d_in[9];

  char* ws = (char*)d_ws;
  size_t off = 0;
  auto alloc = [&](size_t bytes) -> void* {
    void* p = ws + off;
    off += (bytes + 255) & ~(size_t)255;
    return p;
  };
  ushort* kvin = (ushort*)alloc((size_t)BT * NKV * D_ * 2);
  ushort* kvo  = (ushort*)alloc((size_t)BT * NKV * 2048 * 2);
  ushort* qb   = (ushort*)alloc((size_t)BT * NLAT * ADIM * 2);
  ushort* ao   = (ushort*)alloc((size_t)BT * NLAT * ADIM * 2);
  ushort* WqT  = (ushort*)alloc((size_t)D_ * ADIM * 2);
  ushort* WkvT = (ushort*)alloc((size_t)D_ * 2 * ADIM * 2);
  ushort* WoutT = (ushort*)alloc((size_t)ADIM * D_ * 2);

  // 128 KB dynamic LDS for gemm256
  hipFuncSetAttribute((const void*)gemm256,
                      hipFuncAttributeMaxDynamicSharedMemorySize, 131072);

  // 1) weights -> bf16 B^T
  wtrans<<<dim3(ADIM / 64, D_ / 64), 256, 0, stream>>>(Wq, WqT, D_, ADIM);
  wtrans<<<dim3(2 * ADIM / 64, D_ / 64), 256, 0, stream>>>(Wkv, WkvT, D_, 2 * ADIM);
  wtrans<<<dim3(D_ / 64, ADIM / 64), 256, 0, stream>>>(Wout, WoutT, ADIM, D_);

  // 2) LN -> bf16 kv_in
  ln_kernel<<<BT * NKV, 256, 0, stream>>>(latents, x, lnl_w, lnl_b, lnm_w, lnm_b, kvin);

  // 3) q = lat_ln @ Wq (remapped A rows, 0.125 folded)   nwg = 128
  gemm128<1, 1><<<dim3(128), 256, 0, stream>>>(
      kvin, WqT, qb, nullptr, ADIM / 128, 128, D_, ADIM);

  // 4) kv = kv_in @ Wkv  — R5 gemm256 (best measured: 346 us)
  gemm256<<<dim3(MT2 * 8), 512, 131072, stream>>>(kvin, WkvT, kvo);

  // 5) attention (with T14 register prefetch)
  attn_kernel<<<BT * HEADS, 256, 0, stream>>>(qb, kvo, ao);

  // 6) out = ao @ Wout + bout   nwg = 128
  gemm128<0, 2><<<dim3(128), 256, 0, stream>>>(
      ao, WoutT, d_out, bout, D_ / 128, 128, ADIM, D_);
}

// Round 8
// 521.794 us; speedup vs baseline: 1.1520x; 1.0646x over previous
//
#include <hip/hip_runtime.h>
#include <hip/hip_bf16.h>
#include <stdint.h>

// Problem constants
#define B_    8
#define T_    4
#define NLAT  64
#define NMED  2048
#define NKV   2112      // NMED + NLAT
#define D_    1024
#define HEADS 16
#define HD    64
#define ADIM  1024
#define BT    32        // B_*T_

#define GK    1024      // kv-GEMM K
#define GN    2048      // kv-GEMM N
#define GM    67584     // BT*NKV
#define NSLC  32        // GK/32
#define NWG_BIG 2144    // 2112 kv tiles + 32 q tiles (= 8*268)

typedef __attribute__((ext_vector_type(8))) short bf16x8;
typedef __attribute__((ext_vector_type(4))) float f32x4;

__device__ __forceinline__ ushort f2bf(float f) {
  union { float f; uint32_t u; } v; v.f = f;
  return (ushort)((v.u + 0x7fff + ((v.u >> 16) & 1)) >> 16);
}

__device__ __forceinline__ void gload_lds16(const void* g, void* l) {
  __builtin_amdgcn_global_load_lds(
      (const __attribute__((address_space(1))) void*)g,
      (__attribute__((address_space(3))) void*)l, 16, 0, 0);
}

__device__ __forceinline__ f32x4 mfma16(bf16x8 a, bf16x8 b, f32x4 c) {
  return __builtin_amdgcn_mfma_f32_16x16x32_bf16(a, b, c, 0, 0, 0);
}

// ---------------------------------------------------------------------------
// Weight transpose + f32->bf16: dst[n][k] = src[k][n].  src [K][Nm], 64x64 tiles.
__global__ __launch_bounds__(256) void wtrans(const float* __restrict__ src,
                                              ushort* __restrict__ dst,
                                              int K, int Nm) {
  __shared__ float t[64][65];
  const int tr = blockIdx.y, tc = blockIdx.x;
  const int c = threadIdx.x & 63;
  const int r4 = threadIdx.x >> 6;
#pragma unroll
  for (int rr = 0; rr < 16; ++rr) {
    int r = r4 + rr * 4;
    t[r][c] = src[(size_t)(tr * 64 + r) * Nm + tc * 64 + c];
  }
  __syncthreads();
#pragma unroll
  for (int rr = 0; rr < 16; ++rr) {
    int n = r4 + rr * 4;
    dst[(size_t)(tc * 64 + n) * K + tr * 64 + c] = f2bf(t[c][n]);
  }
}

// ---------------------------------------------------------------------------
// LayerNorm -> bf16, writing concatenated kv_in.
__global__ __launch_bounds__(256) void ln_kernel(
    const float* __restrict__ lat, const float* __restrict__ x,
    const float* __restrict__ lnl_w, const float* __restrict__ lnl_b,
    const float* __restrict__ lnm_w, const float* __restrict__ lnm_b,
    ushort* __restrict__ kvin) {
  const int row = blockIdx.x;
  const int bt = row / NKV;
  const int j = row - bt * NKV;
  const float* src;
  const float* w;
  const float* bb;
  if (j < NMED) {
    src = x + ((size_t)bt * NMED + j) * D_;
    w = lnm_w; bb = lnm_b;
  } else {
    src = lat + ((size_t)bt * NLAT + (j - NMED)) * D_;
    w = lnl_w; bb = lnl_b;
  }
  const int tid = threadIdx.x;
  float4 v = ((const float4*)src)[tid];
  float s = v.x + v.y + v.z + v.w;
  float s2 = v.x * v.x + v.y * v.y + v.z * v.z + v.w * v.w;
#pragma unroll
  for (int off = 1; off < 64; off <<= 1) {
    s += __shfl_xor(s, off, 64);
    s2 += __shfl_xor(s2, off, 64);
  }
  __shared__ float red[8];
  const int wave = tid >> 6;
  if ((tid & 63) == 0) { red[wave] = s; red[4 + wave] = s2; }
  __syncthreads();
  float S = red[0] + red[1] + red[2] + red[3];
  float S2 = red[4] + red[5] + red[6] + red[7];
  const float inv = 1.f / (float)D_;
  float mu = S * inv;
  float var = S2 * inv - mu * mu;
  float rs = rsqrtf(var + 1e-5f);
  float4 wv = ((const float4*)w)[tid];
  float4 bv = ((const float4*)bb)[tid];
  ushort4 ov;
  ov.x = f2bf((v.x - mu) * rs * wv.x + bv.x);
  ov.y = f2bf((v.y - mu) * rs * wv.y + bv.y);
  ov.z = f2bf((v.z - mu) * rs * wv.z + bv.z);
  ov.w = f2bf((v.w - mu) * rs * wv.w + bv.w);
  ((ushort4*)(kvin + (size_t)row * D_))[tid] = ov;
}

// ---------------------------------------------------------------------------
// 128x128 GEMM (m97 2-barrier structure, 3 blocks/CU) — used for out-GEMM.
// OUTMODE:2 = f32 + bias
template <int AMODE, int OUTMODE>
__global__ __launch_bounds__(256, 3) void gemm128(const ushort* __restrict__ A,
                                                  const ushort* __restrict__ Bt,
                                                  void* __restrict__ C,
                                                  const float* __restrict__ bias,
                                                  int ntx, int nwg, int K, int ldc) {
  __shared__ ushort lsA[128 * 32];
  __shared__ ushort lsB[128 * 32];
  const int tid = threadIdx.x;
  const int lane = tid & 63;
  const int wave = tid >> 6;
  const int lr = lane & 15;
  const int lg = lane >> 4;
  const int wr = (wave >> 1) * 64;
  const int wc = (wave & 1) * 64;

  const int g = blockIdx.x;
  const int cpx = nwg >> 3;
  const int v = (g & 7) * cpx + (g >> 3);
  const int bx = v % ntx;
  const int by = v / ntx;
  const long brow = (long)by * 128;
  const int bcol = bx * 128;

  const int pcx = lg ^ ((lr >> 1) & 3);

  f32x4 acc[4][4];
#pragma unroll
  for (int m = 0; m < 4; ++m)
#pragma unroll
    for (int n = 0; n < 4; ++n) acc[m][n] = (f32x4){0.f, 0.f, 0.f, 0.f};

  const int s0 = tid, s1 = 256 + tid;
  const int r0 = s0 >> 2, r1 = s1 >> 2;
  const int c0 = (s0 & 3) ^ ((s0 >> 3) & 3);
  const int c1 = (s1 & 3) ^ ((s1 >> 3) & 3);
  const int o0 = (s0 & ~63) * 16;
  const int o1 = (s1 & ~63) * 16;

  long arow0, arow1;
  if (AMODE == 1) {
    int g0 = (int)brow + r0, g1 = (int)brow + r1;
    arow0 = (long)(g0 >> 6) * NKV + NMED + (g0 & 63);
    arow1 = (long)(g1 >> 6) * NKV + NMED + (g1 & 63);
  } else {
    arow0 = brow + r0;
    arow1 = brow + r1;
  }
  const long browB0 = (long)(bcol + r0) * K;
  const long browB1 = (long)(bcol + r1) * K;

  for (int k0 = 0; k0 < K; k0 += 32) {
    gload_lds16(A + arow0 * (long)K + k0 + c0 * 8, (char*)lsA + o0);
    gload_lds16(A + arow1 * (long)K + k0 + c1 * 8, (char*)lsA + o1);
    gload_lds16(Bt + browB0 + k0 + c0 * 8, (char*)lsB + o0);
    gload_lds16(Bt + browB1 + k0 + c1 * 8, (char*)lsB + o1);
    __syncthreads();

    bf16x8 af[4], bf[4];
#pragma unroll
    for (int m = 0; m < 4; ++m)
      af[m] = *(const bf16x8*)((char*)lsA + (wr + m * 16 + lr) * 64 + pcx * 16);
#pragma unroll
    for (int n = 0; n < 4; ++n)
      bf[n] = *(const bf16x8*)((char*)lsB + (wc + n * 16 + lr) * 64 + pcx * 16);
#pragma unroll
    for (int m = 0; m < 4; ++m)
#pragma unroll
      for (int n = 0; n < 4; ++n)
        acc[m][n] = mfma16(bf[n], af[m], acc[m][n]);
    __syncthreads();
  }

#pragma unroll
  for (int m = 0; m < 4; ++m) {
    long row = brow + wr + m * 16 + lr;
#pragma unroll
    for (int n = 0; n < 4; ++n) {
      int coln = bcol + wc + n * 16 + lg * 4;
      long off = row * (long)ldc + coln;
      if (OUTMODE == 2) {
        float4 bv = *(const float4*)(bias + coln);
        float4 o;
        o.x = acc[m][n][0] + bv.x;
        o.y = acc[m][n][1] + bv.y;
        o.z = acc[m][n][2] + bv.z;
        o.w = acc[m][n][3] + bv.w;
        *(float4*)((float*)C + off) = o;
      } else {
        const float sc = (OUTMODE == 1) ? 0.125f : 1.f;
        ushort4 o;
        o.x = f2bf(acc[m][n][0] * sc);
        o.y = f2bf(acc[m][n][1] * sc);
        o.z = f2bf(acc[m][n][2] * sc);
        o.w = f2bf(acc[m][n][3] * sc);
        *(ushort4*)((ushort*)C + off) = o;
      }
    }
  }
}

// ---------------------------------------------------------------------------
// Big GEMM: 256x256 tiles, 8 waves of 128x64, BK=32, 4-slot LDS ring (128 KB),
// stage-ahead 3, counted vmcnt(8)/lgkmcnt(4/8) pipeline (R5 schedule, 346 us).
// NEW: grid covers kv tiles (v<2112) AND q tiles (v>=2112): q tiles remap A
// rows to the latent rows of kvin, use WqT, write qb with 0.125 scale.
__global__ __launch_bounds__(512, 2) void gemm256(const ushort* __restrict__ A,
                                                  const ushort* __restrict__ BtKV,
                                                  const ushort* __restrict__ BtQ,
                                                  ushort* __restrict__ Ckv,
                                                  ushort* __restrict__ Cq) {
  extern __shared__ __align__(16) char smem[];  // 4 slots x (16KB A + 16KB B)
  const int tid = threadIdx.x;
  const int lane = tid & 63;
  const int wv = tid >> 6;
  const int wm = wv >> 2;
  const int wn = wv & 3;
  const int lr = lane & 15;
  const int lg = lane >> 4;

  // bijective XCD swizzle over 2144 = 8*268 blocks
  const int g = blockIdx.x;
  const int v = (g & 7) * (NWG_BIG / 8) + (g >> 3);
  const bool isq = v >= 2112;
  long brow; int bcol;
  const ushort* Bp; ushort* Cp; int ldc;
  if (!isq) {
    brow = (long)(v >> 3) * 256;
    bcol = (v & 7) * 256;
    Bp = BtKV; Cp = Ckv; ldc = GN;
  } else {
    int u = v - 2112;          // 32 q tiles: 8 M x 4 N
    brow = (long)(u >> 2) * 256;
    bcol = (u & 3) * 256;
    Bp = BtQ; Cp = Cq; ldc = ADIM;
  }
  const float sc = isq ? 0.125f : 1.f;

  const int pcx = lg ^ ((lr >> 1) & 3);
  const int rbA = wm * 128 + lr;
  const int rbB = wn * 64 + lr;

  f32x4 acc[8][4];
#pragma unroll
  for (int m = 0; m < 8; ++m)
#pragma unroll
    for (int n = 0; n < 4; ++n) acc[m][n] = (f32x4){0.f, 0.f, 0.f, 0.f};

  const int s0 = tid, s1 = 512 + tid;
  const int r0 = s0 >> 2, r1 = s1 >> 2;
  const int c0 = (s0 & 3) ^ ((s0 >> 3) & 3);
  const int c1 = (s1 & 3) ^ ((s1 >> 3) & 3);
  const int o0 = (s0 & ~63) * 16;
  const int o1 = (s1 & ~63) * 16;

  long arow0, arow1;
  if (isq) {
    int g0 = (int)brow + r0, g1 = (int)brow + r1;
    arow0 = (long)(g0 >> 6) * NKV + NMED + (g0 & 63);
    arow1 = (long)(g1 >> 6) * NKV + NMED + (g1 & 63);
  } else {
    arow0 = brow + r0;
    arow1 = brow + r1;
  }

#define STAGE_A(slc, slot)                                                     \
  {                                                                            \
    long k0 = (long)(slc) * 32;                                                \
    char* db = smem + (slot) * 32768;                                          \
    gload_lds16(A + arow0 * (long)GK + k0 + c0 * 8, db + o0);                  \
    gload_lds16(A + arow1 * (long)GK + k0 + c1 * 8, db + o1);                  \
  }
#define STAGE_B(slc, slot)                                                     \
  {                                                                            \
    long k0 = (long)(slc) * 32;                                                \
    char* db = smem + (slot) * 32768 + 16384;                                  \
    gload_lds16(Bp + (long)(bcol + r0) * GK + k0 + c0 * 8, db + o0);           \
    gload_lds16(Bp + (long)(bcol + r1) * GK + k0 + c1 * 8, db + o1);           \
  }

  bf16x8 a0[4], a1[4], b0[4], b1[4];

  STAGE_A(0, 0); STAGE_B(0, 0);
  STAGE_A(1, 1); STAGE_B(1, 1);
  STAGE_A(2, 2); STAGE_B(2, 2);
  asm volatile("s_waitcnt vmcnt(8)" ::: "memory");
  __builtin_amdgcn_s_barrier();
#pragma unroll
  for (int m = 0; m < 4; ++m)
    a0[m] = *(const bf16x8*)(smem + (rbA + m * 16) * 64 + pcx * 16);
#pragma unroll
  for (int n = 0; n < 4; ++n)
    b0[n] = *(const bf16x8*)(smem + 16384 + (rbB + n * 16) * 64 + pcx * 16);
  __builtin_amdgcn_sched_barrier(0);

#define SLICE(T, BCUR, BNXT)                                                   \
  {                                                                            \
    const int t_ = (T);                                                        \
    const char* sA_ = smem + (t_ & 3) * 32768;                                 \
    const int ts_ = (t_ + 3 < NSLC) ? t_ + 3 : t_;                             \
    const int ws_ = (t_ + 3) & 3;                                              \
    /* ---- phase 0 ---- */                                                    \
    _Pragma("unroll")                                                          \
    for (int m = 0; m < 4; ++m)                                                \
      a1[m] = *(const bf16x8*)(sA_ + (rbA + (m + 4) * 16) * 64 + pcx * 16);    \
    STAGE_A(ts_, ws_);                                                         \
    __builtin_amdgcn_sched_barrier(0);                                         \
    __builtin_amdgcn_s_barrier();                                              \
    asm volatile("s_waitcnt lgkmcnt(4)" ::: "memory");                         \
    __builtin_amdgcn_sched_barrier(0);                                         \
    __builtin_amdgcn_s_setprio(1);                                             \
    _Pragma("unroll")                                                          \
    for (int m = 0; m < 4; ++m)                                                \
      _Pragma("unroll")                                                        \
      for (int n = 0; n < 4; ++n)                                              \
        acc[m][n] = mfma16(BCUR[n], a0[m], acc[m][n]);                         \
    __builtin_amdgcn_s_setprio(0);                                             \
    __builtin_amdgcn_sched_barrier(0);                                         \
    __builtin_amdgcn_s_barrier();                                              \
    /* ---- phase 1 ---- */                                                    \
    STAGE_B(ts_, ws_);                                                         \
    asm volatile("s_waitcnt vmcnt(8)" ::: "memory");                           \
    __builtin_amdgcn_sched_barrier(0);                                         \
    __builtin_amdgcn_s_barrier();                                              \
    {                                                                          \
      const int tn_ = (t_ + 1 < NSLC) ? t_ + 1 : t_;                           \
      const char* nA_ = smem + (tn_ & 3) * 32768;                              \
      const char* nB_ = nA_ + 16384;                                           \
      _Pragma("unroll")                                                        \
      for (int m = 0; m < 4; ++m)                                              \
        a0[m] = *(const bf16x8*)(nA_ + (rbA + m * 16) * 64 + pcx * 16);        \
      _Pragma("unroll")                                                        \
      for (int n = 0; n < 4; ++n)                                              \
        BNXT[n] = *(const bf16x8*)(nB_ + (rbB + n * 16) * 64 + pcx * 16);      \
    }                                                                          \
    __builtin_amdgcn_sched_barrier(0);                                         \
    asm volatile("s_waitcnt lgkmcnt(8)" ::: "memory");                         \
    __builtin_amdgcn_sched_barrier(0);                                         \
    __builtin_amdgcn_s_setprio(1);                                             \
    _Pragma("unroll")                                                          \
    for (int m = 0; m < 4; ++m)                                                \
      _Pragma("unroll")                                                        \
      for (int n = 0; n < 4; ++n)                                              \
        acc[m + 4][n] = mfma16(BCUR[n], a1[m], acc[m + 4][n]);                 \
    __builtin_amdgcn_s_setprio(0);                                             \
    __builtin_amdgcn_sched_barrier(0);                                         \
    __builtin_amdgcn_s_barrier();                                              \
  }

  for (int t = 0; t < NSLC; t += 2) {
    SLICE(t, b0, b1);
    SLICE(t + 1, b1, b0);
  }
#undef SLICE
#undef STAGE_A
#undef STAGE_B

#pragma unroll
  for (int m = 0; m < 8; ++m) {
    long row = brow + wm * 128 + m * 16 + lr;
    ushort* crow = Cp + row * ldc + bcol + wn * 64 + lg * 4;
#pragma unroll
    for (int n = 0; n < 4; ++n) {
      ushort4 o;
      o.x = f2bf(acc[m][n][0] * sc);
      o.y = f2bf(acc[m][n][1] * sc);
      o.z = f2bf(acc[m][n][2] * sc);
      o.w = f2bf(acc[m][n][3] * sc);
      *(ushort4*)(crow + n * 16) = o;
    }
  }
}

// ---------------------------------------------------------------------------
// Flash attention: one block per (bt, h). 4 waves x 16 q-rows. 33 j-tiles of 64.
// K tile in XOR-swizzled LDS; register double-buffered K/V prefetch.
// NEW: swapped QK^T (mfma16(kf, qf)) -> S[j][q] with q = lane&15: j-reduce is
// in-lane + 2 shfl_xor (vs 32 bpermutes); running m/l are per-lane scalars.
// vt columns chunk-XOR'd to cut V-transpose write conflicts.
__global__ __launch_bounds__(256) void attn_kernel(const ushort* __restrict__ q,
                                                   const ushort* __restrict__ kv,
                                                   ushort* __restrict__ o) {
  const int blk = blockIdx.x;
  const int bt = blk >> 4;
  const int h = blk & 15;
  const int tid = threadIdx.x;
  const int wave = tid >> 6;
  const int lane = tid & 63;
  const int lr = lane & 15;
  const int lg = lane >> 4;

  __shared__ ushort vtf[64 * 72];    // V^T tile: row d stride 72, chunk-XOR cols
  __shared__ ushort pl[4][16][72];   // per-wave P tile: [q][j]
  __shared__ ushort kl[64 * 64];     // K tile, rows of 128B, slot-XOR swizzle

  const ushort* qbase = q + (size_t)(bt * 64 + wave * 16) * ADIM + h * HD;
  bf16x8 qf[2];
#pragma unroll
  for (int ks = 0; ks < 2; ++ks)
    qf[ks] = *(const bf16x8*)(qbase + (size_t)lr * ADIM + ks * 32 + lg * 8);

  const ushort* kvb = kv + (size_t)bt * NKV * 2048;
  const int jj = tid >> 2;       // row this thread stages
  const int q4 = tid & 3;        // 16-elem chunk

  f32x4 accO[4];
#pragma unroll
  for (int n = 0; n < 4; ++n) accO[n] = (f32x4){0.f, 0.f, 0.f, 0.f};
  float mrun = -1e30f;
  float lrun = 0.f;

  // prefetch tile 0 into regs
  bf16x8 kr0, kr1, vr0, vr1;
  {
    const ushort* src = kvb + (size_t)jj * 2048 + h * HD + q4 * 16;
    kr0 = *(const bf16x8*)(src);
    kr1 = *(const bf16x8*)(src + 8);
    vr0 = *(const bf16x8*)(src + ADIM);
    vr1 = *(const bf16x8*)(src + ADIM + 8);
  }

  for (int jt = 0; jt < NKV / 64; ++jt) {
    __syncthreads();   // prev tile's kl/vt/pl reads all done

    // staged regs -> LDS
    {
      int p0 = (q4 * 2) ^ (jj & 7);
      int p1 = (q4 * 2 + 1) ^ (jj & 7);
      *(bf16x8*)((char*)kl + jj * 128 + p0 * 16) = kr0;
      *(bf16x8*)((char*)kl + jj * 128 + p1 * 16) = kr1;
      int d0 = q4 * 16;
      int jc = jj >> 3, jb = jj & 7;
#pragma unroll
      for (int e = 0; e < 8; ++e) {
        vtf[(d0 + e) * 72 + (jc ^ (e & 7)) * 8 + jb] = ((const ushort*)&vr0)[e];
        vtf[(d0 + 8 + e) * 72 + (jc ^ (e & 7)) * 8 + jb] = ((const ushort*)&vr1)[e];
      }
    }

    // issue next tile's loads (fly under this tile's compute)
    bf16x8 nk0, nk1, nv0, nv1;
    {
      const int tn = (jt + 1 < NKV / 64) ? jt + 1 : jt;
      const ushort* src = kvb + (size_t)(tn * 64 + jj) * 2048 + h * HD + q4 * 16;
      nk0 = *(const bf16x8*)(src);
      nk1 = *(const bf16x8*)(src + 8);
      nv0 = *(const bf16x8*)(src + ADIM);
      nv1 = *(const bf16x8*)(src + ADIM + 8);
    }
    __syncthreads();   // kl + vtf visible

    // S = K @ Q^T (swapped): lane holds S[j = j0+nj*16+4lg+r][q = lr]
    f32x4 s[4];
#pragma unroll
    for (int nj = 0; nj < 4; ++nj) s[nj] = (f32x4){0.f, 0.f, 0.f, 0.f};
#pragma unroll
    for (int nj = 0; nj < 4; ++nj)
#pragma unroll
      for (int ks = 0; ks < 2; ++ks) {
        int row = nj * 16 + lr;
        int phys = (4 * ks + lg) ^ (lr & 7);
        bf16x8 kf = *(const bf16x8*)((char*)kl + row * 128 + phys * 16);
        s[nj] = mfma16(kf, qf[ks], s[nj]);
      }

    // Online softmax: per-lane q = lr; reduce over j = in-lane 16 + 2 shuffles
    float mloc = s[0][0];
#pragma unroll
    for (int nj = 0; nj < 4; ++nj)
#pragma unroll
      for (int r = 0; r < 4; ++r) mloc = fmaxf(mloc, s[nj][r]);
    mloc = fmaxf(mloc, __shfl_xor(mloc, 16, 64));
    mloc = fmaxf(mloc, __shfl_xor(mloc, 32, 64));
    float mn = fmaxf(mrun, mloc);
    float corr = __expf(mrun - mn);
    mrun = mn;
    float ps = 0.f;
#pragma unroll
    for (int nj = 0; nj < 4; ++nj)
#pragma unroll
      for (int r = 0; r < 4; ++r) {
        float pv = __expf(s[nj][r] - mn);
        s[nj][r] = pv;
        ps += pv;
      }
    ps += __shfl_xor(ps, 16, 64);
    ps += __shfl_xor(ps, 32, 64);
    lrun = lrun * corr + ps;
    // broadcast corr to accO's q-layout (q = 4*lg + r lives in lane 4*lg+r)
    float corrq[4];
#pragma unroll
    for (int r = 0; r < 4; ++r) corrq[r] = __shfl(corr, lg * 4 + r, 64);
#pragma unroll
    for (int n = 0; n < 4; ++n)
#pragma unroll
      for (int r = 0; r < 4; ++r) accO[n][r] *= corrq[r];

    // P -> LDS: pl[wave][q = lr][j-local = nj*16 + 4lg + r]
#pragma unroll
    for (int nj = 0; nj < 4; ++nj)
#pragma unroll
      for (int r = 0; r < 4; ++r)
        pl[wave][lr][nj * 16 + 4 * lg + r] = f2bf(s[nj][r]);
    __syncthreads();   // pl visible

    bf16x8 pf[2];
#pragma unroll
    for (int ks = 0; ks < 2; ++ks)
      pf[ks] = *(const bf16x8*)&pl[wave][lr][ks * 32 + lg * 8];
#pragma unroll
    for (int nd = 0; nd < 4; ++nd)
#pragma unroll
      for (int ks = 0; ks < 2; ++ks) {
        bf16x8 vf = *(const bf16x8*)&vtf[(nd * 16 + lr) * 72 +
                                         ((4 * ks + lg) ^ (lr & 7)) * 8];
        accO[nd] = mfma16(pf[ks], vf, accO[nd]);
      }

    kr0 = nk0; kr1 = nk1; vr0 = nv0; vr1 = nv1;
  }

  // O = accO / l  (l for q = 4lg+r lives in lane 4lg+r)
  float lq[4];
#pragma unroll
  for (int r = 0; r < 4; ++r) lq[r] = __shfl(lrun, lg * 4 + r, 64);
#pragma unroll
  for (int nd = 0; nd < 4; ++nd)
#pragma unroll
    for (int r = 0; r < 4; ++r) {
      float vv = accO[nd][r] / lq[r];
      int row = bt * 64 + wave * 16 + lg * 4 + r;
      o[(size_t)row * ADIM + h * HD + nd * 16 + lr] = f2bf(vv);
    }
}

// ---------------------------------------------------------------------------
extern "C" void kernel_launch(void* const* d_in, const int* in_sizes, int n_in,
                              void* d_out, int out_size, void* d_ws, size_t ws_size,
                              hipStream_t stream) {
  const float* latents = (const float*)d_in[0];
  const float* x = (const float*)d_in[1];
  const float* Wq = (const float*)d_in[2];
  const float* Wkv = (const float*)d_in[3];
  const float* Wout = (const float*)d_in[4];
  const float* bout = (const float*)d_in[5];
  const float* lnl_w = (const float*)d_in[6];
  const float* lnl_b = (const float*)d_in[7];
  const float* lnm_w = (const float*)d_in[8];
  const float* lnm_b = (const float*)d_in[9];

  char* ws = (char*)d_ws;
  size_t off = 0;
  auto alloc = [&](size_t bytes) -> void* {
    void* p = ws + off;
    off += (bytes + 255) & ~(size_t)255;
    return p;
  };
  ushort* kvin = (ushort*)alloc((size_t)BT * NKV * D_ * 2);
  ushort* kvo  = (ushort*)alloc((size_t)BT * NKV * 2048 * 2);
  ushort* qb   = (ushort*)alloc((size_t)BT * NLAT * ADIM * 2);
  ushort* ao   = (ushort*)alloc((size_t)BT * NLAT * ADIM * 2);
  ushort* WqT  = (ushort*)alloc((size_t)D_ * ADIM * 2);
  ushort* WkvT = (ushort*)alloc((size_t)D_ * 2 * ADIM * 2);
  ushort* WoutT = (ushort*)alloc((size_t)ADIM * D_ * 2);

  // 128 KB dynamic LDS for gemm256
  hipFuncSetAttribute((const void*)gemm256,
                      hipFuncAttributeMaxDynamicSharedMemorySize, 131072);

  // 1) weights -> bf16 B^T
  wtrans<<<dim3(ADIM / 64, D_ / 64), 256, 0, stream>>>(Wq, WqT, D_, ADIM);
  wtrans<<<dim3(2 * ADIM / 64, D_ / 64), 256, 0, stream>>>(Wkv, WkvT, D_, 2 * ADIM);
  wtrans<<<dim3(D_ / 64, ADIM / 64), 256, 0, stream>>>(Wout, WoutT, ADIM, D_);

  // 2) LN -> bf16 kv_in
  ln_kernel<<<BT * NKV, 256, 0, stream>>>(latents, x, lnl_w, lnl_b, lnm_w, lnm_b, kvin);

  // 3+4) kv = kv_in @ Wkv  AND  q = lat_ln @ Wq (folded into one big grid)
  gemm256<<<dim3(NWG_BIG), 512, 131072, stream>>>(kvin, WkvT, WqT, kvo, qb);

  // 5) attention
  attn_kernel<<<BT * HEADS, 256, 0, stream>>>(qb, kvo, ao);

  // 6) out = ao @ Wout + bout   nwg = 128
  gemm128<0, 2><<<dim3(128), 256, 0, stream>>>(
      ao, WoutT, d_out, bout, D_ / 128, 128, ADIM, D_);
}

// Round 9
// 515.213 us; speedup vs baseline: 1.1667x; 1.0128x over previous
//
#include <hip/hip_runtime.h>
#include <hip/hip_bf16.h>
#include <stdint.h>

// Problem constants
#define B_    8
#define T_    4
#define NLAT  64
#define NMED  2048
#define NKV   2112      // NMED + NLAT
#define D_    1024
#define HEADS 16
#define HD    64
#define ADIM  1024
#define BT    32        // B_*T_

#define GK    1024      // kv-GEMM K
#define GN    2048      // kv-GEMM N
#define GM    67584     // BT*NKV
#define NSLC  32        // GK/32
#define NWG_BIG 2144    // 2112 kv tiles + 32 q tiles (= 8*268)

typedef __attribute__((ext_vector_type(8))) short bf16x8;
typedef __attribute__((ext_vector_type(4))) float f32x4;

__device__ __forceinline__ ushort f2bf(float f) {
  union { float f; uint32_t u; } v; v.f = f;
  return (ushort)((v.u + 0x7fff + ((v.u >> 16) & 1)) >> 16);
}

__device__ __forceinline__ void gload_lds16(const void* g, void* l) {
  __builtin_amdgcn_global_load_lds(
      (const __attribute__((address_space(1))) void*)g,
      (__attribute__((address_space(3))) void*)l, 16, 0, 0);
}

__device__ __forceinline__ f32x4 mfma16(bf16x8 a, bf16x8 b, f32x4 c) {
  return __builtin_amdgcn_mfma_f32_16x16x32_bf16(a, b, c, 0, 0, 0);
}

// ---------------------------------------------------------------------------
// Weight transpose + f32->bf16: dst[n][k] = src[k][n].  src [K][Nm], 64x64 tiles.
__global__ __launch_bounds__(256) void wtrans(const float* __restrict__ src,
                                              ushort* __restrict__ dst,
                                              int K, int Nm) {
  __shared__ float t[64][65];
  const int tr = blockIdx.y, tc = blockIdx.x;
  const int c = threadIdx.x & 63;
  const int r4 = threadIdx.x >> 6;
#pragma unroll
  for (int rr = 0; rr < 16; ++rr) {
    int r = r4 + rr * 4;
    t[r][c] = src[(size_t)(tr * 64 + r) * Nm + tc * 64 + c];
  }
  __syncthreads();
#pragma unroll
  for (int rr = 0; rr < 16; ++rr) {
    int n = r4 + rr * 4;
    dst[(size_t)(tc * 64 + n) * K + tr * 64 + c] = f2bf(t[c][n]);
  }
}

// ---------------------------------------------------------------------------
// LayerNorm -> bf16, writing concatenated kv_in.
__global__ __launch_bounds__(256) void ln_kernel(
    const float* __restrict__ lat, const float* __restrict__ x,
    const float* __restrict__ lnl_w, const float* __restrict__ lnl_b,
    const float* __restrict__ lnm_w, const float* __restrict__ lnm_b,
    ushort* __restrict__ kvin) {
  const int row = blockIdx.x;
  const int bt = row / NKV;
  const int j = row - bt * NKV;
  const float* src;
  const float* w;
  const float* bb;
  if (j < NMED) {
    src = x + ((size_t)bt * NMED + j) * D_;
    w = lnm_w; bb = lnm_b;
  } else {
    src = lat + ((size_t)bt * NLAT + (j - NMED)) * D_;
    w = lnl_w; bb = lnl_b;
  }
  const int tid = threadIdx.x;
  float4 v = ((const float4*)src)[tid];
  float s = v.x + v.y + v.z + v.w;
  float s2 = v.x * v.x + v.y * v.y + v.z * v.z + v.w * v.w;
#pragma unroll
  for (int off = 1; off < 64; off <<= 1) {
    s += __shfl_xor(s, off, 64);
    s2 += __shfl_xor(s2, off, 64);
  }
  __shared__ float red[8];
  const int wave = tid >> 6;
  if ((tid & 63) == 0) { red[wave] = s; red[4 + wave] = s2; }
  __syncthreads();
  float S = red[0] + red[1] + red[2] + red[3];
  float S2 = red[4] + red[5] + red[6] + red[7];
  const float inv = 1.f / (float)D_;
  float mu = S * inv;
  float var = S2 * inv - mu * mu;
  float rs = rsqrtf(var + 1e-5f);
  float4 wv = ((const float4*)w)[tid];
  float4 bv = ((const float4*)bb)[tid];
  ushort4 ov;
  ov.x = f2bf((v.x - mu) * rs * wv.x + bv.x);
  ov.y = f2bf((v.y - mu) * rs * wv.y + bv.y);
  ov.z = f2bf((v.z - mu) * rs * wv.z + bv.z);
  ov.w = f2bf((v.w - mu) * rs * wv.w + bv.w);
  ((ushort4*)(kvin + (size_t)row * D_))[tid] = ov;
}

// ---------------------------------------------------------------------------
// 128x128 GEMM (m97 2-barrier structure, 3 blocks/CU) — used for out-GEMM.
template <int AMODE, int OUTMODE>
__global__ __launch_bounds__(256, 3) void gemm128(const ushort* __restrict__ A,
                                                  const ushort* __restrict__ Bt,
                                                  void* __restrict__ C,
                                                  const float* __restrict__ bias,
                                                  int ntx, int nwg, int K, int ldc) {
  __shared__ ushort lsA[128 * 32];
  __shared__ ushort lsB[128 * 32];
  const int tid = threadIdx.x;
  const int lane = tid & 63;
  const int wave = tid >> 6;
  const int lr = lane & 15;
  const int lg = lane >> 4;
  const int wr = (wave >> 1) * 64;
  const int wc = (wave & 1) * 64;

  const int g = blockIdx.x;
  const int cpx = nwg >> 3;
  const int v = (g & 7) * cpx + (g >> 3);
  const int bx = v % ntx;
  const int by = v / ntx;
  const long brow = (long)by * 128;
  const int bcol = bx * 128;

  const int pcx = lg ^ ((lr >> 1) & 3);

  f32x4 acc[4][4];
#pragma unroll
  for (int m = 0; m < 4; ++m)
#pragma unroll
    for (int n = 0; n < 4; ++n) acc[m][n] = (f32x4){0.f, 0.f, 0.f, 0.f};

  const int s0 = tid, s1 = 256 + tid;
  const int r0 = s0 >> 2, r1 = s1 >> 2;
  const int c0 = (s0 & 3) ^ ((s0 >> 3) & 3);
  const int c1 = (s1 & 3) ^ ((s1 >> 3) & 3);
  const int o0 = (s0 & ~63) * 16;
  const int o1 = (s1 & ~63) * 16;

  long arow0, arow1;
  if (AMODE == 1) {
    int g0 = (int)brow + r0, g1 = (int)brow + r1;
    arow0 = (long)(g0 >> 6) * NKV + NMED + (g0 & 63);
    arow1 = (long)(g1 >> 6) * NKV + NMED + (g1 & 63);
  } else {
    arow0 = brow + r0;
    arow1 = brow + r1;
  }
  const long browB0 = (long)(bcol + r0) * K;
  const long browB1 = (long)(bcol + r1) * K;

  for (int k0 = 0; k0 < K; k0 += 32) {
    gload_lds16(A + arow0 * (long)K + k0 + c0 * 8, (char*)lsA + o0);
    gload_lds16(A + arow1 * (long)K + k0 + c1 * 8, (char*)lsA + o1);
    gload_lds16(Bt + browB0 + k0 + c0 * 8, (char*)lsB + o0);
    gload_lds16(Bt + browB1 + k0 + c1 * 8, (char*)lsB + o1);
    __syncthreads();

    bf16x8 af[4], bf[4];
#pragma unroll
    for (int m = 0; m < 4; ++m)
      af[m] = *(const bf16x8*)((char*)lsA + (wr + m * 16 + lr) * 64 + pcx * 16);
#pragma unroll
    for (int n = 0; n < 4; ++n)
      bf[n] = *(const bf16x8*)((char*)lsB + (wc + n * 16 + lr) * 64 + pcx * 16);
#pragma unroll
    for (int m = 0; m < 4; ++m)
#pragma unroll
      for (int n = 0; n < 4; ++n)
        acc[m][n] = mfma16(bf[n], af[m], acc[m][n]);
    __syncthreads();
  }

#pragma unroll
  for (int m = 0; m < 4; ++m) {
    long row = brow + wr + m * 16 + lr;
#pragma unroll
    for (int n = 0; n < 4; ++n) {
      int coln = bcol + wc + n * 16 + lg * 4;
      long off = row * (long)ldc + coln;
      if (OUTMODE == 2) {
        float4 bv = *(const float4*)(bias + coln);
        float4 o;
        o.x = acc[m][n][0] + bv.x;
        o.y = acc[m][n][1] + bv.y;
        o.z = acc[m][n][2] + bv.z;
        o.w = acc[m][n][3] + bv.w;
        *(float4*)((float*)C + off) = o;
      } else {
        const float sc = (OUTMODE == 1) ? 0.125f : 1.f;
        ushort4 o;
        o.x = f2bf(acc[m][n][0] * sc);
        o.y = f2bf(acc[m][n][1] * sc);
        o.z = f2bf(acc[m][n][2] * sc);
        o.w = f2bf(acc[m][n][3] * sc);
        *(ushort4*)((ushort*)C + off) = o;
      }
    }
  }
}

// ---------------------------------------------------------------------------
// Big GEMM: 256x256 tiles, 8 waves of 128x64, BK=32, 4-slot LDS ring (128 KB),
// stage-ahead 3, counted vmcnt(8)/lgkmcnt(4/8) pipeline.  Grid covers kv tiles
// (v<2112) AND q tiles (v>=2112, lat-row remap, WqT, 0.125 scale).  FROZEN.
__global__ __launch_bounds__(512, 2) void gemm256(const ushort* __restrict__ A,
                                                  const ushort* __restrict__ BtKV,
                                                  const ushort* __restrict__ BtQ,
                                                  ushort* __restrict__ Ckv,
                                                  ushort* __restrict__ Cq) {
  extern __shared__ __align__(16) char smem[];  // 4 slots x (16KB A + 16KB B)
  const int tid = threadIdx.x;
  const int lane = tid & 63;
  const int wv = tid >> 6;
  const int wm = wv >> 2;
  const int wn = wv & 3;
  const int lr = lane & 15;
  const int lg = lane >> 4;

  const int g = blockIdx.x;
  const int v = (g & 7) * (NWG_BIG / 8) + (g >> 3);
  const bool isq = v >= 2112;
  long brow; int bcol;
  const ushort* Bp; ushort* Cp; int ldc;
  if (!isq) {
    brow = (long)(v >> 3) * 256;
    bcol = (v & 7) * 256;
    Bp = BtKV; Cp = Ckv; ldc = GN;
  } else {
    int u = v - 2112;
    brow = (long)(u >> 2) * 256;
    bcol = (u & 3) * 256;
    Bp = BtQ; Cp = Cq; ldc = ADIM;
  }
  const float sc = isq ? 0.125f : 1.f;

  const int pcx = lg ^ ((lr >> 1) & 3);
  const int rbA = wm * 128 + lr;
  const int rbB = wn * 64 + lr;

  f32x4 acc[8][4];
#pragma unroll
  for (int m = 0; m < 8; ++m)
#pragma unroll
    for (int n = 0; n < 4; ++n) acc[m][n] = (f32x4){0.f, 0.f, 0.f, 0.f};

  const int s0 = tid, s1 = 512 + tid;
  const int r0 = s0 >> 2, r1 = s1 >> 2;
  const int c0 = (s0 & 3) ^ ((s0 >> 3) & 3);
  const int c1 = (s1 & 3) ^ ((s1 >> 3) & 3);
  const int o0 = (s0 & ~63) * 16;
  const int o1 = (s1 & ~63) * 16;

  long arow0, arow1;
  if (isq) {
    int g0 = (int)brow + r0, g1 = (int)brow + r1;
    arow0 = (long)(g0 >> 6) * NKV + NMED + (g0 & 63);
    arow1 = (long)(g1 >> 6) * NKV + NMED + (g1 & 63);
  } else {
    arow0 = brow + r0;
    arow1 = brow + r1;
  }

#define STAGE_A(slc, slot)                                                     \
  {                                                                            \
    long k0 = (long)(slc) * 32;                                                \
    char* db = smem + (slot) * 32768;                                          \
    gload_lds16(A + arow0 * (long)GK + k0 + c0 * 8, db + o0);                  \
    gload_lds16(A + arow1 * (long)GK + k0 + c1 * 8, db + o1);                  \
  }
#define STAGE_B(slc, slot)                                                     \
  {                                                                            \
    long k0 = (long)(slc) * 32;                                                \
    char* db = smem + (slot) * 32768 + 16384;                                  \
    gload_lds16(Bp + (long)(bcol + r0) * GK + k0 + c0 * 8, db + o0);           \
    gload_lds16(Bp + (long)(bcol + r1) * GK + k0 + c1 * 8, db + o1);           \
  }

  bf16x8 a0[4], a1[4], b0[4], b1[4];

  STAGE_A(0, 0); STAGE_B(0, 0);
  STAGE_A(1, 1); STAGE_B(1, 1);
  STAGE_A(2, 2); STAGE_B(2, 2);
  asm volatile("s_waitcnt vmcnt(8)" ::: "memory");
  __builtin_amdgcn_s_barrier();
#pragma unroll
  for (int m = 0; m < 4; ++m)
    a0[m] = *(const bf16x8*)(smem + (rbA + m * 16) * 64 + pcx * 16);
#pragma unroll
  for (int n = 0; n < 4; ++n)
    b0[n] = *(const bf16x8*)(smem + 16384 + (rbB + n * 16) * 64 + pcx * 16);
  __builtin_amdgcn_sched_barrier(0);

#define SLICE(T, BCUR, BNXT)                                                   \
  {                                                                            \
    const int t_ = (T);                                                        \
    const char* sA_ = smem + (t_ & 3) * 32768;                                 \
    const int ts_ = (t_ + 3 < NSLC) ? t_ + 3 : t_;                             \
    const int ws_ = (t_ + 3) & 3;                                              \
    /* ---- phase 0 ---- */                                                    \
    _Pragma("unroll")                                                          \
    for (int m = 0; m < 4; ++m)                                                \
      a1[m] = *(const bf16x8*)(sA_ + (rbA + (m + 4) * 16) * 64 + pcx * 16);    \
    STAGE_A(ts_, ws_);                                                         \
    __builtin_amdgcn_sched_barrier(0);                                         \
    __builtin_amdgcn_s_barrier();                                              \
    asm volatile("s_waitcnt lgkmcnt(4)" ::: "memory");                         \
    __builtin_amdgcn_sched_barrier(0);                                         \
    __builtin_amdgcn_s_setprio(1);                                             \
    _Pragma("unroll")                                                          \
    for (int m = 0; m < 4; ++m)                                                \
      _Pragma("unroll")                                                        \
      for (int n = 0; n < 4; ++n)                                              \
        acc[m][n] = mfma16(BCUR[n], a0[m], acc[m][n]);                         \
    __builtin_amdgcn_s_setprio(0);                                             \
    __builtin_amdgcn_sched_barrier(0);                                         \
    __builtin_amdgcn_s_barrier();                                              \
    /* ---- phase 1 ---- */                                                    \
    STAGE_B(ts_, ws_);                                                         \
    asm volatile("s_waitcnt vmcnt(8)" ::: "memory");                           \
    __builtin_amdgcn_sched_barrier(0);                                         \
    __builtin_amdgcn_s_barrier();                                              \
    {                                                                          \
      const int tn_ = (t_ + 1 < NSLC) ? t_ + 1 : t_;                           \
      const char* nA_ = smem + (tn_ & 3) * 32768;                              \
      const char* nB_ = nA_ + 16384;                                           \
      _Pragma("unroll")                                                        \
      for (int m = 0; m < 4; ++m)                                              \
        a0[m] = *(const bf16x8*)(nA_ + (rbA + m * 16) * 64 + pcx * 16);        \
      _Pragma("unroll")                                                        \
      for (int n = 0; n < 4; ++n)                                              \
        BNXT[n] = *(const bf16x8*)(nB_ + (rbB + n * 16) * 64 + pcx * 16);      \
    }                                                                          \
    __builtin_amdgcn_sched_barrier(0);                                         \
    asm volatile("s_waitcnt lgkmcnt(8)" ::: "memory");                         \
    __builtin_amdgcn_sched_barrier(0);                                         \
    __builtin_amdgcn_s_setprio(1);                                             \
    _Pragma("unroll")                                                          \
    for (int m = 0; m < 4; ++m)                                                \
      _Pragma("unroll")                                                        \
      for (int n = 0; n < 4; ++n)                                              \
        acc[m + 4][n] = mfma16(BCUR[n], a1[m], acc[m + 4][n]);                 \
    __builtin_amdgcn_s_setprio(0);                                             \
    __builtin_amdgcn_sched_barrier(0);                                         \
    __builtin_amdgcn_s_barrier();                                              \
  }

  for (int t = 0; t < NSLC; t += 2) {
    SLICE(t, b0, b1);
    SLICE(t + 1, b1, b0);
  }
#undef SLICE
#undef STAGE_A
#undef STAGE_B

#pragma unroll
  for (int m = 0; m < 8; ++m) {
    long row = brow + wm * 128 + m * 16 + lr;
    ushort* crow = Cp + row * ldc + bcol + wn * 64 + lg * 4;
#pragma unroll
    for (int n = 0; n < 4; ++n) {
      ushort4 o;
      o.x = f2bf(acc[m][n][0] * sc);
      o.y = f2bf(acc[m][n][1] * sc);
      o.z = f2bf(acc[m][n][2] * sc);
      o.w = f2bf(acc[m][n][3] * sc);
      *(ushort4*)(crow + n * 16) = o;
    }
  }
}

// ---------------------------------------------------------------------------
// Flash attention: one block per (bt, h). 4 waves x 16 q-rows. 33 j-tiles of 64.
// NEW vs R8: kl/vtf double-buffered -> ONE barrier per tile (was 3).
//  - pl is per-wave (write+read by the same wave): no barrier needed,
//    compiler orders via lgkmcnt.
//  - buffer-overwrite hazard removed by dbuf: wave Y's write of buf[t&1] at
//    top of iter t+2 happens after bar(t+1), which requires every wave's
//    iter-t reads of buf[t&1] (between bar(t) and bar(t+1)) to be done.
//  - T5 setprio around both MFMA clusters (independent blocks regime).
__global__ __launch_bounds__(256) void attn_kernel(const ushort* __restrict__ q,
                                                   const ushort* __restrict__ kv,
                                                   ushort* __restrict__ o) {
  const int blk = blockIdx.x;
  const int bt = blk >> 4;
  const int h = blk & 15;
  const int tid = threadIdx.x;
  const int wave = tid >> 6;
  const int lane = tid & 63;
  const int lr = lane & 15;
  const int lg = lane >> 4;

  __shared__ ushort klb[2][64 * 64];   // K tiles, rows of 128B, slot-XOR swizzle
  __shared__ ushort vtb[2][64 * 72];   // V^T tiles, chunk-XOR cols
  __shared__ ushort pl[4][16][72];     // per-wave P tile: [q][j]

  const ushort* qbase = q + (size_t)(bt * 64 + wave * 16) * ADIM + h * HD;
  bf16x8 qf[2];
#pragma unroll
  for (int ks = 0; ks < 2; ++ks)
    qf[ks] = *(const bf16x8*)(qbase + (size_t)lr * ADIM + ks * 32 + lg * 8);

  const ushort* kvb = kv + (size_t)bt * NKV * 2048;
  const int jj = tid >> 2;       // row this thread stages
  const int q4 = tid & 3;        // 16-elem chunk

  f32x4 accO[4];
#pragma unroll
  for (int n = 0; n < 4; ++n) accO[n] = (f32x4){0.f, 0.f, 0.f, 0.f};
  float mrun = -1e30f;
  float lrun = 0.f;

  // prefetch tile 0 into regs
  bf16x8 kr0, kr1, vr0, vr1;
  {
    const ushort* src = kvb + (size_t)jj * 2048 + h * HD + q4 * 16;
    kr0 = *(const bf16x8*)(src);
    kr1 = *(const bf16x8*)(src + 8);
    vr0 = *(const bf16x8*)(src + ADIM);
    vr1 = *(const bf16x8*)(src + ADIM + 8);
  }

  for (int jt = 0; jt < NKV / 64; ++jt) {
    const int pb = jt & 1;
    ushort* kl = klb[pb];
    ushort* vtf = vtb[pb];

    // staged regs -> LDS (dbuf: no barrier needed before the write)
    {
      int p0 = (q4 * 2) ^ (jj & 7);
      int p1 = (q4 * 2 + 1) ^ (jj & 7);
      *(bf16x8*)((char*)kl + jj * 128 + p0 * 16) = kr0;
      *(bf16x8*)((char*)kl + jj * 128 + p1 * 16) = kr1;
      int d0 = q4 * 16;
      int jc = jj >> 3, jb = jj & 7;
#pragma unroll
      for (int e = 0; e < 8; ++e) {
        vtf[(d0 + e) * 72 + (jc ^ (e & 7)) * 8 + jb] = ((const ushort*)&vr0)[e];
        vtf[(d0 + 8 + e) * 72 + (jc ^ (e & 7)) * 8 + jb] = ((const ushort*)&vr1)[e];
      }
    }

    // issue next tile's loads (fly under this tile's compute)
    bf16x8 nk0, nk1, nv0, nv1;
    {
      const int tn = (jt + 1 < NKV / 64) ? jt + 1 : jt;
      const ushort* src = kvb + (size_t)(tn * 64 + jj) * 2048 + h * HD + q4 * 16;
      nk0 = *(const bf16x8*)(src);
      nk1 = *(const bf16x8*)(src + 8);
      nv0 = *(const bf16x8*)(src + ADIM);
      nv1 = *(const bf16x8*)(src + ADIM + 8);
    }
    __syncthreads();   // the ONE barrier: kl/vtf of tile jt visible to all waves

    // S = K @ Q^T (swapped): lane holds S[j = nj*16+4lg+r][q = lr]
    f32x4 s[4];
#pragma unroll
    for (int nj = 0; nj < 4; ++nj) s[nj] = (f32x4){0.f, 0.f, 0.f, 0.f};
    __builtin_amdgcn_s_setprio(1);
#pragma unroll
    for (int nj = 0; nj < 4; ++nj)
#pragma unroll
      for (int ks = 0; ks < 2; ++ks) {
        int row = nj * 16 + lr;
        int phys = (4 * ks + lg) ^ (lr & 7);
        bf16x8 kf = *(const bf16x8*)((char*)kl + row * 128 + phys * 16);
        s[nj] = mfma16(kf, qf[ks], s[nj]);
      }
    __builtin_amdgcn_s_setprio(0);

    // Online softmax: per-lane q = lr; reduce over j = in-lane + 2 shuffles
    float mloc = s[0][0];
#pragma unroll
    for (int nj = 0; nj < 4; ++nj)
#pragma unroll
      for (int r = 0; r < 4; ++r) mloc = fmaxf(mloc, s[nj][r]);
    mloc = fmaxf(mloc, __shfl_xor(mloc, 16, 64));
    mloc = fmaxf(mloc, __shfl_xor(mloc, 32, 64));
    float mn = fmaxf(mrun, mloc);
    float corr = __expf(mrun - mn);
    mrun = mn;
    float ps = 0.f;
#pragma unroll
    for (int nj = 0; nj < 4; ++nj)
#pragma unroll
      for (int r = 0; r < 4; ++r) {
        float pv = __expf(s[nj][r] - mn);
        s[nj][r] = pv;
        ps += pv;
      }
    ps += __shfl_xor(ps, 16, 64);
    ps += __shfl_xor(ps, 32, 64);
    lrun = lrun * corr + ps;
    float corrq[4];
#pragma unroll
    for (int r = 0; r < 4; ++r) corrq[r] = __shfl(corr, lg * 4 + r, 64);
#pragma unroll
    for (int n = 0; n < 4; ++n)
#pragma unroll
      for (int r = 0; r < 4; ++r) accO[n][r] *= corrq[r];

    // P -> per-wave LDS region; same-wave read-back (no barrier: lgkmcnt orders)
#pragma unroll
    for (int nj = 0; nj < 4; ++nj)
#pragma unroll
      for (int r = 0; r < 4; ++r)
        pl[wave][lr][nj * 16 + 4 * lg + r] = f2bf(s[nj][r]);

    bf16x8 pf[2];
#pragma unroll
    for (int ks = 0; ks < 2; ++ks)
      pf[ks] = *(const bf16x8*)&pl[wave][lr][ks * 32 + lg * 8];
    __builtin_amdgcn_s_setprio(1);
#pragma unroll
    for (int nd = 0; nd < 4; ++nd)
#pragma unroll
      for (int ks = 0; ks < 2; ++ks) {
        bf16x8 vf = *(const bf16x8*)&vtf[(nd * 16 + lr) * 72 +
                                         ((4 * ks + lg) ^ (lr & 7)) * 8];
        accO[nd] = mfma16(pf[ks], vf, accO[nd]);
      }
    __builtin_amdgcn_s_setprio(0);

    kr0 = nk0; kr1 = nk1; vr0 = nv0; vr1 = nv1;
  }

  // O = accO / l  (l for q = 4lg+r lives in lane 4lg+r)
  float lq[4];
#pragma unroll
  for (int r = 0; r < 4; ++r) lq[r] = __shfl(lrun, lg * 4 + r, 64);
#pragma unroll
  for (int nd = 0; nd < 4; ++nd)
#pragma unroll
    for (int r = 0; r < 4; ++r) {
      float vv = accO[nd][r] / lq[r];
      int row = bt * 64 + wave * 16 + lg * 4 + r;
      o[(size_t)row * ADIM + h * HD + nd * 16 + lr] = f2bf(vv);
    }
}

// ---------------------------------------------------------------------------
extern "C" void kernel_launch(void* const* d_in, const int* in_sizes, int n_in,
                              void* d_out, int out_size, void* d_ws, size_t ws_size,
                              hipStream_t stream) {
  const float* latents = (const float*)d_in[0];
  const float* x = (const float*)d_in[1];
  const float* Wq = (const float*)d_in[2];
  const float* Wkv = (const float*)d_in[3];
  const float* Wout = (const float*)d_in[4];
  const float* bout = (const float*)d_in[5];
  const float* lnl_w = (const float*)d_in[6];
  const float* lnl_b = (const float*)d_in[7];
  const float* lnm_w = (const float*)d_in[8];
  const float* lnm_b = (const float*)d_in[9];

  char* ws = (char*)d_ws;
  size_t off = 0;
  auto alloc = [&](size_t bytes) -> void* {
    void* p = ws + off;
    off += (bytes + 255) & ~(size_t)255;
    return p;
  };
  ushort* kvin = (ushort*)alloc((size_t)BT * NKV * D_ * 2);
  ushort* kvo  = (ushort*)alloc((size_t)BT * NKV * 2048 * 2);
  ushort* qb   = (ushort*)alloc((size_t)BT * NLAT * ADIM * 2);
  ushort* ao   = (ushort*)alloc((size_t)BT * NLAT * ADIM * 2);
  ushort* WqT  = (ushort*)alloc((size_t)D_ * ADIM * 2);
  ushort* WkvT = (ushort*)alloc((size_t)D_ * 2 * ADIM * 2);
  ushort* WoutT = (ushort*)alloc((size_t)ADIM * D_ * 2);

  // 128 KB dynamic LDS for gemm256
  hipFuncSetAttribute((const void*)gemm256,
                      hipFuncAttributeMaxDynamicSharedMemorySize, 131072);

  // 1) weights -> bf16 B^T
  wtrans<<<dim3(ADIM / 64, D_ / 64), 256, 0, stream>>>(Wq, WqT, D_, ADIM);
  wtrans<<<dim3(2 * ADIM / 64, D_ / 64), 256, 0, stream>>>(Wkv, WkvT, D_, 2 * ADIM);
  wtrans<<<dim3(D_ / 64, ADIM / 64), 256, 0, stream>>>(Wout, WoutT, ADIM, D_);

  // 2) LN -> bf16 kv_in
  ln_kernel<<<BT * NKV, 256, 0, stream>>>(latents, x, lnl_w, lnl_b, lnm_w, lnm_b, kvin);

  // 3+4) kv = kv_in @ Wkv  AND  q = lat_ln @ Wq (one big grid)
  gemm256<<<dim3(NWG_BIG), 512, 131072, stream>>>(kvin, WkvT, WqT, kvo, qb);

  // 5) attention (1-barrier dbuf loop + setprio)
  attn_kernel<<<BT * HEADS, 256, 0, stream>>>(qb, kvo, ao);

  // 6) out = ao @ Wout + bout   nwg = 128
  gemm128<0, 2><<<dim3(128), 256, 0, stream>>>(
      ao, WoutT, d_out, bout, D_ / 128, 128, ADIM, D_);
}

// Round 10
// 495.479 us; speedup vs baseline: 1.2132x; 1.0398x over previous
//
#include <hip/hip_runtime.h>
#include <hip/hip_bf16.h>
#include <stdint.h>

// Problem constants
#define B_    8
#define T_    4
#define NLAT  64
#define NMED  2048
#define NKV   2112      // NMED + NLAT
#define D_    1024
#define HEADS 16
#define HD    64
#define ADIM  1024
#define BT    32        // B_*T_

#define GK    1024      // kv-GEMM K
#define GN    2048      // kv-GEMM N
#define GM    67584     // BT*NKV
#define NSLC  32        // GK/32
#define NWGB  4288      // 4224 kv tiles (528x8 of 128x256) + 64 q tiles (= 8*536)

typedef __attribute__((ext_vector_type(8))) short bf16x8;
typedef __attribute__((ext_vector_type(4))) float f32x4;

__device__ __forceinline__ ushort f2bf(float f) {
  union { float f; uint32_t u; } v; v.f = f;
  return (ushort)((v.u + 0x7fff + ((v.u >> 16) & 1)) >> 16);
}

__device__ __forceinline__ void gload_lds16(const void* g, void* l) {
  __builtin_amdgcn_global_load_lds(
      (const __attribute__((address_space(1))) void*)g,
      (__attribute__((address_space(3))) void*)l, 16, 0, 0);
}

__device__ __forceinline__ f32x4 mfma16(bf16x8 a, bf16x8 b, f32x4 c) {
  return __builtin_amdgcn_mfma_f32_16x16x32_bf16(a, b, c, 0, 0, 0);
}

// ---------------------------------------------------------------------------
// All three weight transposes in ONE launch.  64x64 tiles; 1024 blocks:
// [0,256) Wq (16x16 tiles), [256,768) Wkv (16x32), [768,1024) Wout (16x16).
__global__ __launch_bounds__(256) void wtrans_all(
    const float* __restrict__ Wq, const float* __restrict__ Wkv,
    const float* __restrict__ Wout, ushort* __restrict__ WqT,
    ushort* __restrict__ WkvT, ushort* __restrict__ WoutT) {
  __shared__ float t[64][65];
  int b = blockIdx.x;
  const float* src; ushort* dst; int K, Nm, tr, tc;
  if (b < 256) {
    src = Wq; dst = WqT; K = 1024; Nm = 1024; tr = b >> 4; tc = b & 15;
  } else if (b < 768) {
    b -= 256; src = Wkv; dst = WkvT; K = 1024; Nm = 2048; tr = b >> 5; tc = b & 31;
  } else {
    b -= 768; src = Wout; dst = WoutT; K = 1024; Nm = 1024; tr = b >> 4; tc = b & 15;
  }
  const int c = threadIdx.x & 63;
  const int r4 = threadIdx.x >> 6;
#pragma unroll
  for (int rr = 0; rr < 16; ++rr) {
    int r = r4 + rr * 4;
    t[r][c] = src[(size_t)(tr * 64 + r) * Nm + tc * 64 + c];
  }
  __syncthreads();
#pragma unroll
  for (int rr = 0; rr < 16; ++rr) {
    int n = r4 + rr * 4;
    dst[(size_t)(tc * 64 + n) * K + tr * 64 + c] = f2bf(t[c][n]);
  }
}

// ---------------------------------------------------------------------------
// LayerNorm -> bf16 kv_in.  ONE WAVE PER ROW (no LDS, no block barrier):
// 4 rows per 256-thread block; lane handles 16 elems (4x float4).
__global__ __launch_bounds__(256) void ln_kernel(
    const float* __restrict__ lat, const float* __restrict__ x,
    const float* __restrict__ lnl_w, const float* __restrict__ lnl_b,
    const float* __restrict__ lnm_w, const float* __restrict__ lnm_b,
    ushort* __restrict__ kvin) {
  const int wave = threadIdx.x >> 6;
  const int lane = threadIdx.x & 63;
  const int row = blockIdx.x * 4 + wave;
  const int bt = row / NKV;
  const int j = row - bt * NKV;
  const float* src;
  const float* w;
  const float* bb;
  if (j < NMED) {
    src = x + ((size_t)bt * NMED + j) * D_;
    w = lnm_w; bb = lnm_b;
  } else {
    src = lat + ((size_t)bt * NLAT + (j - NMED)) * D_;
    w = lnl_w; bb = lnl_b;
  }
  float4 v[4];
  float s = 0.f, s2 = 0.f;
#pragma unroll
  for (int c = 0; c < 4; ++c) {
    v[c] = ((const float4*)src)[c * 64 + lane];
    s += v[c].x + v[c].y + v[c].z + v[c].w;
    s2 += v[c].x * v[c].x + v[c].y * v[c].y + v[c].z * v[c].z + v[c].w * v[c].w;
  }
#pragma unroll
  for (int off = 1; off < 64; off <<= 1) {
    s += __shfl_xor(s, off, 64);
    s2 += __shfl_xor(s2, off, 64);
  }
  const float inv = 1.f / (float)D_;
  float mu = s * inv;
  float var = s2 * inv - mu * mu;
  float rs = rsqrtf(var + 1e-5f);
  ushort* dst = kvin + (size_t)row * D_;
#pragma unroll
  for (int c = 0; c < 4; ++c) {
    float4 wv = ((const float4*)w)[c * 64 + lane];
    float4 bv = ((const float4*)bb)[c * 64 + lane];
    ushort4 ov;
    ov.x = f2bf((v[c].x - mu) * rs * wv.x + bv.x);
    ov.y = f2bf((v[c].y - mu) * rs * wv.y + bv.y);
    ov.z = f2bf((v[c].z - mu) * rs * wv.z + bv.z);
    ov.w = f2bf((v[c].w - mu) * rs * wv.w + bv.w);
    ((ushort4*)dst)[c * 64 + lane] = ov;
  }
}

// ---------------------------------------------------------------------------
// Big GEMM (R3 structure — best measured 338 us): 128x256 tile, 8 waves of
// 64x64, BK=32, 2 LDS buffers (48 KB static) -> 2 blocks/CU, counted vmcnt(3)
// (never 0 in loop), 2 barriers/slice, chunk-XOR swizzle both-sides,
// swapped-operand MFMA, ushort4 stores.  Grid 4288 = 8*536 bijective XCD:
// v<4224 -> kv tile (by=v>>3, bx=v&7); v>=4224 -> q tile (lat-row remap,
// WqT, 0.125 scale; 16 M x 4 N of 128x256).
__global__ __launch_bounds__(512, 4) void gemm_big(const ushort* __restrict__ A,
                                                   const ushort* __restrict__ BtKV,
                                                   const ushort* __restrict__ BtQ,
                                                   ushort* __restrict__ Ckv,
                                                   ushort* __restrict__ Cq) {
  __shared__ __align__(16) char smem[2 * 24576];  // per buf: 8 KB A + 16 KB B
  const int tid = threadIdx.x;
  const int lane = tid & 63;
  const int wv = tid >> 6;   // 0..7
  const int wm = wv >> 2;    // 0..1  (M half: 64 rows)
  const int wn = wv & 3;     // 0..3  (N quarter: 64 cols)
  const int lr = lane & 15;
  const int lg = lane >> 4;

  const int g = blockIdx.x;
  const int v = (g & 7) * (NWGB / 8) + (g >> 3);
  const bool isq = v >= 4224;
  long brow; int bcol;
  const ushort* Bp; ushort* Cp; int ldc;
  if (!isq) {
    brow = (long)(v >> 3) * 128;
    bcol = (v & 7) * 256;
    Bp = BtKV; Cp = Ckv; ldc = GN;
  } else {
    int u = v - 4224;          // 64 q tiles: 16 M x 4 N
    brow = (long)(u >> 2) * 128;
    bcol = (u & 3) * 256;
    Bp = BtQ; Cp = Cq; ldc = ADIM;
  }
  const float sc = isq ? 0.125f : 1.f;

  const int pcx = lg ^ ((lr >> 1) & 3);  // physical 16B-chunk for frag reads

  f32x4 acc[4][4];
#pragma unroll
  for (int m = 0; m < 4; ++m)
#pragma unroll
    for (int n = 0; n < 4; ++n) acc[m][n] = (f32x4){0.f, 0.f, 0.f, 0.f};

  // staging decode: slot s -> row = s>>2, logical chunk = (s&3)^((s>>3)&3)
  const int rA = tid >> 2;
  const int lc = (tid & 3) ^ ((tid >> 3) & 3);
  const int offA = (tid & ~63) * 16;             // wave-uniform byte base
  const int rB1 = 128 + (tid >> 2);
  const int offB1 = 8192 + offA;

  long arow;
  if (isq) {
    int g0 = (int)brow + rA;
    arow = (long)(g0 >> 6) * NKV + NMED + (g0 & 63);
  } else {
    arow = brow + rA;
  }

#define STAGE(buf, kt)                                                         \
  {                                                                            \
    long k0 = (long)(kt) * 32;                                                 \
    char* dbA = smem + (buf) * 24576;                                          \
    char* dbB = dbA + 8192;                                                    \
    gload_lds16(A + arow * (long)GK + k0 + lc * 8, dbA + offA);                \
    gload_lds16(Bp + (long)(bcol + rA) * GK + k0 + lc * 8, dbB + offA);        \
    gload_lds16(Bp + (long)(bcol + rB1) * GK + k0 + lc * 8, dbB + offB1);      \
  }

  // prologue: tile 0 -> buf 0 (3 loads in flight)
  STAGE(0, 0);

  for (int t = 0; t < NSLC; ++t) {
    const int p = t & 1;
    __builtin_amdgcn_s_barrier();              // (A) prev iter's reads of ~p done
    asm volatile("" ::: "memory");
    const int ts = (t + 1 < NSLC) ? t + 1 : t; // dummy restage at tail
    STAGE(p ^ 1, ts);
    asm volatile("s_waitcnt vmcnt(3)" ::: "memory");  // tile t landed; t+1 flying
    __builtin_amdgcn_s_barrier();              // (B) tile t visible to all waves
    asm volatile("" ::: "memory");

    const char* bufA = smem + p * 24576;
    const char* bufB = bufA + 8192;
    bf16x8 af[4], bf[4];
#pragma unroll
    for (int m = 0; m < 4; ++m) {
      int row = wm * 64 + m * 16 + lr;
      af[m] = *(const bf16x8*)(bufA + row * 64 + pcx * 16);
    }
#pragma unroll
    for (int n = 0; n < 4; ++n) {
      int row = wn * 64 + n * 16 + lr;
      bf[n] = *(const bf16x8*)(bufB + row * 64 + pcx * 16);
    }
    __builtin_amdgcn_s_setprio(1);
#pragma unroll
    for (int m = 0; m < 4; ++m)
#pragma unroll
      for (int n = 0; n < 4; ++n)
        acc[m][n] = mfma16(bf[n], af[m], acc[m][n]);   // swapped operands
    __builtin_amdgcn_s_setprio(0);
  }
#undef STAGE

  // epilogue: lane owns row ...+lr, 4 consecutive cols per frag (ushort4)
#pragma unroll
  for (int m = 0; m < 4; ++m) {
    long row = brow + wm * 64 + m * 16 + lr;
    ushort* crow = Cp + row * ldc + bcol + wn * 64 + lg * 4;
#pragma unroll
    for (int n = 0; n < 4; ++n) {
      ushort4 o;
      o.x = f2bf(acc[m][n][0] * sc);
      o.y = f2bf(acc[m][n][1] * sc);
      o.z = f2bf(acc[m][n][2] * sc);
      o.w = f2bf(acc[m][n][3] * sc);
      *(ushort4*)(crow + n * 16) = o;
    }
  }
}

// ---------------------------------------------------------------------------
// out-GEMM: 64x128 tiles -> 256 blocks (full GPU; was 128).  Same m97
// structure / swizzle / swapped-operand epilogue.  f32 out + bias.
__global__ __launch_bounds__(256, 3) void gemm_out(const ushort* __restrict__ A,
                                                   const ushort* __restrict__ Bt,
                                                   float* __restrict__ C,
                                                   const float* __restrict__ bias) {
  __shared__ ushort lsA[64 * 32];    // 4 KB
  __shared__ ushort lsB[128 * 32];   // 8 KB
  const int tid = threadIdx.x;
  const int lane = tid & 63;
  const int wave = tid >> 6;
  const int lr = lane & 15;
  const int lg = lane >> 4;
  const int wr = (wave >> 1) * 32;   // 2 M halves of 32
  const int wc = (wave & 1) * 64;    // 2 N halves of 64

  const int g = blockIdx.x;
  const int v = (g & 7) * 32 + (g >> 3);   // nwg = 256 = 8*32
  const int bx = v & 7;                    // 8 N tiles of 128
  const int by = v >> 3;                   // 32 M tiles of 64
  const long brow = (long)by * 64;
  const int bcol = bx * 128;

  const int pcx = lg ^ ((lr >> 1) & 3);

  f32x4 acc[2][4];
#pragma unroll
  for (int m = 0; m < 2; ++m)
#pragma unroll
    for (int n = 0; n < 4; ++n) acc[m][n] = (f32x4){0.f, 0.f, 0.f, 0.f};

  const int rA = tid >> 2;                       // A rows 0..63 (1 load)
  const int lc = (tid & 3) ^ ((tid >> 3) & 3);
  const int offA = (tid & ~63) * 16;
  const int rB1 = 64 + (tid >> 2);               // B rows 64..127 (2nd load)
  const int offB1 = 4096 + offA;

  for (int k0 = 0; k0 < ADIM; k0 += 32) {
    gload_lds16(A + (brow + rA) * (long)ADIM + k0 + lc * 8, (char*)lsA + offA);
    gload_lds16(Bt + (long)(bcol + rA) * ADIM + k0 + lc * 8, (char*)lsB + offA);
    gload_lds16(Bt + (long)(bcol + rB1) * ADIM + k0 + lc * 8, (char*)lsB + offB1);
    __syncthreads();

    bf16x8 af[2], bf[4];
#pragma unroll
    for (int m = 0; m < 2; ++m)
      af[m] = *(const bf16x8*)((char*)lsA + (wr + m * 16 + lr) * 64 + pcx * 16);
#pragma unroll
    for (int n = 0; n < 4; ++n)
      bf[n] = *(const bf16x8*)((char*)lsB + (wc + n * 16 + lr) * 64 + pcx * 16);
#pragma unroll
    for (int m = 0; m < 2; ++m)
#pragma unroll
      for (int n = 0; n < 4; ++n)
        acc[m][n] = mfma16(bf[n], af[m], acc[m][n]);
    __syncthreads();
  }

#pragma unroll
  for (int m = 0; m < 2; ++m) {
    long row = brow + wr + m * 16 + lr;
#pragma unroll
    for (int n = 0; n < 4; ++n) {
      int coln = bcol + wc + n * 16 + lg * 4;
      float4 bv = *(const float4*)(bias + coln);
      float4 o;
      o.x = acc[m][n][0] + bv.x;
      o.y = acc[m][n][1] + bv.y;
      o.z = acc[m][n][2] + bv.z;
      o.w = acc[m][n][3] + bv.w;
      *(float4*)(C + row * (long)D_ + coln) = o;
    }
  }
}

// ---------------------------------------------------------------------------
// Flash attention (R9 version, unchanged): one block per (bt,h), 4 waves x 16
// q-rows, 33 j-tiles, dbuf kl/vtf -> ONE barrier/tile, swapped QK^T softmax,
// register K/V prefetch, setprio around MFMA clusters.
__global__ __launch_bounds__(256) void attn_kernel(const ushort* __restrict__ q,
                                                   const ushort* __restrict__ kv,
                                                   ushort* __restrict__ o) {
  const int blk = blockIdx.x;
  const int bt = blk >> 4;
  const int h = blk & 15;
  const int tid = threadIdx.x;
  const int wave = tid >> 6;
  const int lane = tid & 63;
  const int lr = lane & 15;
  const int lg = lane >> 4;

  __shared__ ushort klb[2][64 * 64];
  __shared__ ushort vtb[2][64 * 72];
  __shared__ ushort pl[4][16][72];

  const ushort* qbase = q + (size_t)(bt * 64 + wave * 16) * ADIM + h * HD;
  bf16x8 qf[2];
#pragma unroll
  for (int ks = 0; ks < 2; ++ks)
    qf[ks] = *(const bf16x8*)(qbase + (size_t)lr * ADIM + ks * 32 + lg * 8);

  const ushort* kvb = kv + (size_t)bt * NKV * 2048;
  const int jj = tid >> 2;
  const int q4 = tid & 3;

  f32x4 accO[4];
#pragma unroll
  for (int n = 0; n < 4; ++n) accO[n] = (f32x4){0.f, 0.f, 0.f, 0.f};
  float mrun = -1e30f;
  float lrun = 0.f;

  bf16x8 kr0, kr1, vr0, vr1;
  {
    const ushort* src = kvb + (size_t)jj * 2048 + h * HD + q4 * 16;
    kr0 = *(const bf16x8*)(src);
    kr1 = *(const bf16x8*)(src + 8);
    vr0 = *(const bf16x8*)(src + ADIM);
    vr1 = *(const bf16x8*)(src + ADIM + 8);
  }

  for (int jt = 0; jt < NKV / 64; ++jt) {
    const int pb = jt & 1;
    ushort* kl = klb[pb];
    ushort* vtf = vtb[pb];

    {
      int p0 = (q4 * 2) ^ (jj & 7);
      int p1 = (q4 * 2 + 1) ^ (jj & 7);
      *(bf16x8*)((char*)kl + jj * 128 + p0 * 16) = kr0;
      *(bf16x8*)((char*)kl + jj * 128 + p1 * 16) = kr1;
      int d0 = q4 * 16;
      int jc = jj >> 3, jb = jj & 7;
#pragma unroll
      for (int e = 0; e < 8; ++e) {
        vtf[(d0 + e) * 72 + (jc ^ (e & 7)) * 8 + jb] = ((const ushort*)&vr0)[e];
        vtf[(d0 + 8 + e) * 72 + (jc ^ (e & 7)) * 8 + jb] = ((const ushort*)&vr1)[e];
      }
    }

    bf16x8 nk0, nk1, nv0, nv1;
    {
      const int tn = (jt + 1 < NKV / 64) ? jt + 1 : jt;
      const ushort* src = kvb + (size_t)(tn * 64 + jj) * 2048 + h * HD + q4 * 16;
      nk0 = *(const bf16x8*)(src);
      nk1 = *(const bf16x8*)(src + 8);
      nv0 = *(const bf16x8*)(src + ADIM);
      nv1 = *(const bf16x8*)(src + ADIM + 8);
    }
    __syncthreads();

    f32x4 s[4];
#pragma unroll
    for (int nj = 0; nj < 4; ++nj) s[nj] = (f32x4){0.f, 0.f, 0.f, 0.f};
    __builtin_amdgcn_s_setprio(1);
#pragma unroll
    for (int nj = 0; nj < 4; ++nj)
#pragma unroll
      for (int ks = 0; ks < 2; ++ks) {
        int row = nj * 16 + lr;
        int phys = (4 * ks + lg) ^ (lr & 7);
        bf16x8 kf = *(const bf16x8*)((char*)kl + row * 128 + phys * 16);
        s[nj] = mfma16(kf, qf[ks], s[nj]);
      }
    __builtin_amdgcn_s_setprio(0);

    float mloc = s[0][0];
#pragma unroll
    for (int nj = 0; nj < 4; ++nj)
#pragma unroll
      for (int r = 0; r < 4; ++r) mloc = fmaxf(mloc, s[nj][r]);
    mloc = fmaxf(mloc, __shfl_xor(mloc, 16, 64));
    mloc = fmaxf(mloc, __shfl_xor(mloc, 32, 64));
    float mn = fmaxf(mrun, mloc);
    float corr = __expf(mrun - mn);
    mrun = mn;
    float ps = 0.f;
#pragma unroll
    for (int nj = 0; nj < 4; ++nj)
#pragma unroll
      for (int r = 0; r < 4; ++r) {
        float pv = __expf(s[nj][r] - mn);
        s[nj][r] = pv;
        ps += pv;
      }
    ps += __shfl_xor(ps, 16, 64);
    ps += __shfl_xor(ps, 32, 64);
    lrun = lrun * corr + ps;
    float corrq[4];
#pragma unroll
    for (int r = 0; r < 4; ++r) corrq[r] = __shfl(corr, lg * 4 + r, 64);
#pragma unroll
    for (int n = 0; n < 4; ++n)
#pragma unroll
      for (int r = 0; r < 4; ++r) accO[n][r] *= corrq[r];

#pragma unroll
    for (int nj = 0; nj < 4; ++nj)
#pragma unroll
      for (int r = 0; r < 4; ++r)
        pl[wave][lr][nj * 16 + 4 * lg + r] = f2bf(s[nj][r]);

    bf16x8 pf[2];
#pragma unroll
    for (int ks = 0; ks < 2; ++ks)
      pf[ks] = *(const bf16x8*)&pl[wave][lr][ks * 32 + lg * 8];
    __builtin_amdgcn_s_setprio(1);
#pragma unroll
    for (int nd = 0; nd < 4; ++nd)
#pragma unroll
      for (int ks = 0; ks < 2; ++ks) {
        bf16x8 vf = *(const bf16x8*)&vtf[(nd * 16 + lr) * 72 +
                                         ((4 * ks + lg) ^ (lr & 7)) * 8];
        accO[nd] = mfma16(pf[ks], vf, accO[nd]);
      }
    __builtin_amdgcn_s_setprio(0);

    kr0 = nk0; kr1 = nk1; vr0 = nv0; vr1 = nv1;
  }

  float lq[4];
#pragma unroll
  for (int r = 0; r < 4; ++r) lq[r] = __shfl(lrun, lg * 4 + r, 64);
#pragma unroll
  for (int nd = 0; nd < 4; ++nd)
#pragma unroll
    for (int r = 0; r < 4; ++r) {
      float vv = accO[nd][r] / lq[r];
      int row = bt * 64 + wave * 16 + lg * 4 + r;
      o[(size_t)row * ADIM + h * HD + nd * 16 + lr] = f2bf(vv);
    }
}

// ---------------------------------------------------------------------------
extern "C" void kernel_launch(void* const* d_in, const int* in_sizes, int n_in,
                              void* d_out, int out_size, void* d_ws, size_t ws_size,
                              hipStream_t stream) {
  const float* latents = (const float*)d_in[0];
  const float* x = (const float*)d_in[1];
  const float* Wq = (const float*)d_in[2];
  const float* Wkv = (const float*)d_in[3];
  const float* Wout = (const float*)d_in[4];
  const float* bout = (const float*)d_in[5];
  const float* lnl_w = (const float*)d_in[6];
  const float* lnl_b = (const float*)d_in[7];
  const float* lnm_w = (const float*)d_in[8];
  const float* lnm_b = (const float*)d_in[9];

  char* ws = (char*)d_ws;
  size_t off = 0;
  auto alloc = [&](size_t bytes) -> void* {
    void* p = ws + off;
    off += (bytes + 255) & ~(size_t)255;
    return p;
  };
  ushort* kvin = (ushort*)alloc((size_t)BT * NKV * D_ * 2);
  ushort* kvo  = (ushort*)alloc((size_t)BT * NKV * 2048 * 2);
  ushort* qb   = (ushort*)alloc((size_t)BT * NLAT * ADIM * 2);
  ushort* ao   = (ushort*)alloc((size_t)BT * NLAT * ADIM * 2);
  ushort* WqT  = (ushort*)alloc((size_t)D_ * ADIM * 2);
  ushort* WkvT = (ushort*)alloc((size_t)D_ * 2 * ADIM * 2);
  ushort* WoutT = (ushort*)alloc((size_t)ADIM * D_ * 2);

  // 1) all weight transposes, one launch
  wtrans_all<<<dim3(1024), 256, 0, stream>>>(Wq, Wkv, Wout, WqT, WkvT, WoutT);

  // 2) LN -> bf16 kv_in (wave-per-row)
  ln_kernel<<<GM / 4, 256, 0, stream>>>(latents, x, lnl_w, lnl_b, lnm_w, lnm_b, kvin);

  // 3+4) kv = kv_in @ Wkv  AND  q = lat_ln @ Wq (one grid, R3 structure)
  gemm_big<<<dim3(NWGB), 512, 0, stream>>>(kvin, WkvT, WqT, kvo, qb);

  // 5) attention
  attn_kernel<<<BT * HEADS, 256, 0, stream>>>(qb, kvo, ao);

  // 6) out = ao @ Wout + bout (64x128 tiles, 256 blocks)
  gemm_out<<<dim3(256), 256, 0, stream>>>(ao, WoutT, (float*)d_out, bout);
}

// Round 11
// 488.247 us; speedup vs baseline: 1.2311x; 1.0148x over previous
//
#include <hip/hip_runtime.h>
#include <hip/hip_bf16.h>
#include <stdint.h>

// Problem constants
#define B_    8
#define T_    4
#define NLAT  64
#define NMED  2048
#define NKV   2112      // NMED + NLAT
#define D_    1024
#define HEADS 16
#define HD    64
#define ADIM  1024
#define BT    32        // B_*T_

#define GK    1024      // kv-GEMM K
#define GN    2048      // kv-GEMM N
#define GM    67584     // BT*NKV
#define NSLC  32        // GK/32
#define NWGB  4288      // 4224 kv tiles (528x8 of 128x256) + 64 q tiles (= 8*536)
#define LNBLK 16896     // GM/4 LN blocks
#define PREPBLK (LNBLK + 1024)

typedef __attribute__((ext_vector_type(8))) short bf16x8;
typedef __attribute__((ext_vector_type(4))) float f32x4;

__device__ __forceinline__ ushort f2bf(float f) {
  union { float f; uint32_t u; } v; v.f = f;
  return (ushort)((v.u + 0x7fff + ((v.u >> 16) & 1)) >> 16);
}

__device__ __forceinline__ void gload_lds16(const void* g, void* l) {
  __builtin_amdgcn_global_load_lds(
      (const __attribute__((address_space(1))) void*)g,
      (__attribute__((address_space(3))) void*)l, 16, 0, 0);
}

__device__ __forceinline__ f32x4 mfma16(bf16x8 a, bf16x8 b, f32x4 c) {
  return __builtin_amdgcn_mfma_f32_16x16x32_bf16(a, b, c, 0, 0, 0);
}

// ---------------------------------------------------------------------------
// prep: LN (wave-per-row) for blocks [0, LNBLK) + the three weight transposes
// for blocks [LNBLK, LNBLK+1024).  Branch is block-uniform.  16.5 KB static
// LDS (transpose path only) leaves LN at its 8-blocks/CU thread cap.
__global__ __launch_bounds__(256) void prep_kernel(
    const float* __restrict__ lat, const float* __restrict__ x,
    const float* __restrict__ lnl_w, const float* __restrict__ lnl_b,
    const float* __restrict__ lnm_w, const float* __restrict__ lnm_b,
    ushort* __restrict__ kvin,
    const float* __restrict__ Wq, const float* __restrict__ Wkv,
    const float* __restrict__ Wout, ushort* __restrict__ WqT,
    ushort* __restrict__ WkvT, ushort* __restrict__ WoutT) {
  __shared__ float t[64][65];

  if (blockIdx.x >= LNBLK) {
    // ---- weight transpose path ----
    int b = blockIdx.x - LNBLK;
    const float* src; ushort* dst; int Nm, tr, tc;
    if (b < 256) {
      src = Wq; dst = WqT; Nm = 1024; tr = b >> 4; tc = b & 15;
    } else if (b < 768) {
      b -= 256; src = Wkv; dst = WkvT; Nm = 2048; tr = b >> 5; tc = b & 31;
    } else {
      b -= 768; src = Wout; dst = WoutT; Nm = 1024; tr = b >> 4; tc = b & 15;
    }
    const int c = threadIdx.x & 63;
    const int r4 = threadIdx.x >> 6;
#pragma unroll
    for (int rr = 0; rr < 16; ++rr) {
      int r = r4 + rr * 4;
      t[r][c] = src[(size_t)(tr * 64 + r) * Nm + tc * 64 + c];
    }
    __syncthreads();
#pragma unroll
    for (int rr = 0; rr < 16; ++rr) {
      int n = r4 + rr * 4;
      dst[(size_t)(tc * 64 + n) * 1024 + tr * 64 + c] = f2bf(t[c][n]);
    }
    return;
  }

  // ---- LN path: one wave per row, 4 rows per block ----
  const int wave = threadIdx.x >> 6;
  const int lane = threadIdx.x & 63;
  const int row = blockIdx.x * 4 + wave;
  const int bt = row / NKV;
  const int j = row - bt * NKV;
  const float* src;
  const float* w;
  const float* bb;
  if (j < NMED) {
    src = x + ((size_t)bt * NMED + j) * D_;
    w = lnm_w; bb = lnm_b;
  } else {
    src = lat + ((size_t)bt * NLAT + (j - NMED)) * D_;
    w = lnl_w; bb = lnl_b;
  }
  float4 v[4];
  float s = 0.f, s2 = 0.f;
#pragma unroll
  for (int c = 0; c < 4; ++c) {
    v[c] = ((const float4*)src)[c * 64 + lane];
    s += v[c].x + v[c].y + v[c].z + v[c].w;
    s2 += v[c].x * v[c].x + v[c].y * v[c].y + v[c].z * v[c].z + v[c].w * v[c].w;
  }
#pragma unroll
  for (int off = 1; off < 64; off <<= 1) {
    s += __shfl_xor(s, off, 64);
    s2 += __shfl_xor(s2, off, 64);
  }
  const float inv = 1.f / (float)D_;
  float mu = s * inv;
  float var = s2 * inv - mu * mu;
  float rs = rsqrtf(var + 1e-5f);
  ushort* dst = kvin + (size_t)row * D_;
#pragma unroll
  for (int c = 0; c < 4; ++c) {
    float4 wv = ((const float4*)w)[c * 64 + lane];
    float4 bv = ((const float4*)bb)[c * 64 + lane];
    ushort4 ov;
    ov.x = f2bf((v[c].x - mu) * rs * wv.x + bv.x);
    ov.y = f2bf((v[c].y - mu) * rs * wv.y + bv.y);
    ov.z = f2bf((v[c].z - mu) * rs * wv.z + bv.z);
    ov.w = f2bf((v[c].w - mu) * rs * wv.w + bv.w);
    ((ushort4*)dst)[c * 64 + lane] = ov;
  }
}

// ---------------------------------------------------------------------------
// Big GEMM (R3 structure, frozen): 128x256 tile, 8 waves of 64x64, BK=32,
// 2 LDS buffers (48 KB) -> 2 blocks/CU, counted vmcnt(3), 2 barriers/slice,
// chunk-XOR swizzle both-sides, swapped-operand MFMA, ushort4 stores.
// Grid 4288 = 8*536 bijective XCD; v>=4224 -> q tile (lat-row remap, WqT,
// 0.125 scale).
__global__ __launch_bounds__(512, 4) void gemm_big(const ushort* __restrict__ A,
                                                   const ushort* __restrict__ BtKV,
                                                   const ushort* __restrict__ BtQ,
                                                   ushort* __restrict__ Ckv,
                                                   ushort* __restrict__ Cq) {
  __shared__ __align__(16) char smem[2 * 24576];  // per buf: 8 KB A + 16 KB B
  const int tid = threadIdx.x;
  const int lane = tid & 63;
  const int wv = tid >> 6;
  const int wm = wv >> 2;
  const int wn = wv & 3;
  const int lr = lane & 15;
  const int lg = lane >> 4;

  const int g = blockIdx.x;
  const int v = (g & 7) * (NWGB / 8) + (g >> 3);
  const bool isq = v >= 4224;
  long brow; int bcol;
  const ushort* Bp; ushort* Cp; int ldc;
  if (!isq) {
    brow = (long)(v >> 3) * 128;
    bcol = (v & 7) * 256;
    Bp = BtKV; Cp = Ckv; ldc = GN;
  } else {
    int u = v - 4224;
    brow = (long)(u >> 2) * 128;
    bcol = (u & 3) * 256;
    Bp = BtQ; Cp = Cq; ldc = ADIM;
  }
  const float sc = isq ? 0.125f : 1.f;

  const int pcx = lg ^ ((lr >> 1) & 3);

  f32x4 acc[4][4];
#pragma unroll
  for (int m = 0; m < 4; ++m)
#pragma unroll
    for (int n = 0; n < 4; ++n) acc[m][n] = (f32x4){0.f, 0.f, 0.f, 0.f};

  const int rA = tid >> 2;
  const int lc = (tid & 3) ^ ((tid >> 3) & 3);
  const int offA = (tid & ~63) * 16;
  const int rB1 = 128 + (tid >> 2);
  const int offB1 = 8192 + offA;

  long arow;
  if (isq) {
    int g0 = (int)brow + rA;
    arow = (long)(g0 >> 6) * NKV + NMED + (g0 & 63);
  } else {
    arow = brow + rA;
  }

#define STAGE(buf, kt)                                                         \
  {                                                                            \
    long k0 = (long)(kt) * 32;                                                 \
    char* dbA = smem + (buf) * 24576;                                          \
    char* dbB = dbA + 8192;                                                    \
    gload_lds16(A + arow * (long)GK + k0 + lc * 8, dbA + offA);                \
    gload_lds16(Bp + (long)(bcol + rA) * GK + k0 + lc * 8, dbB + offA);        \
    gload_lds16(Bp + (long)(bcol + rB1) * GK + k0 + lc * 8, dbB + offB1);      \
  }

  STAGE(0, 0);

  for (int t = 0; t < NSLC; ++t) {
    const int p = t & 1;
    __builtin_amdgcn_s_barrier();
    asm volatile("" ::: "memory");
    const int ts = (t + 1 < NSLC) ? t + 1 : t;
    STAGE(p ^ 1, ts);
    asm volatile("s_waitcnt vmcnt(3)" ::: "memory");
    __builtin_amdgcn_s_barrier();
    asm volatile("" ::: "memory");

    const char* bufA = smem + p * 24576;
    const char* bufB = bufA + 8192;
    bf16x8 af[4], bf[4];
#pragma unroll
    for (int m = 0; m < 4; ++m) {
      int row = wm * 64 + m * 16 + lr;
      af[m] = *(const bf16x8*)(bufA + row * 64 + pcx * 16);
    }
#pragma unroll
    for (int n = 0; n < 4; ++n) {
      int row = wn * 64 + n * 16 + lr;
      bf[n] = *(const bf16x8*)(bufB + row * 64 + pcx * 16);
    }
    __builtin_amdgcn_s_setprio(1);
#pragma unroll
    for (int m = 0; m < 4; ++m)
#pragma unroll
      for (int n = 0; n < 4; ++n)
        acc[m][n] = mfma16(bf[n], af[m], acc[m][n]);
    __builtin_amdgcn_s_setprio(0);
  }
#undef STAGE

#pragma unroll
  for (int m = 0; m < 4; ++m) {
    long row = brow + wm * 64 + m * 16 + lr;
    ushort* crow = Cp + row * ldc + bcol + wn * 64 + lg * 4;
#pragma unroll
    for (int n = 0; n < 4; ++n) {
      ushort4 o;
      o.x = f2bf(acc[m][n][0] * sc);
      o.y = f2bf(acc[m][n][1] * sc);
      o.z = f2bf(acc[m][n][2] * sc);
      o.w = f2bf(acc[m][n][3] * sc);
      *(ushort4*)(crow + n * 16) = o;
    }
  }
}

// ---------------------------------------------------------------------------
// out-GEMM: 64x128 tiles -> 256 blocks, m97 structure, f32 out + bias.
__global__ __launch_bounds__(256, 3) void gemm_out(const ushort* __restrict__ A,
                                                   const ushort* __restrict__ Bt,
                                                   float* __restrict__ C,
                                                   const float* __restrict__ bias) {
  __shared__ ushort lsA[64 * 32];
  __shared__ ushort lsB[128 * 32];
  const int tid = threadIdx.x;
  const int lane = tid & 63;
  const int wave = tid >> 6;
  const int lr = lane & 15;
  const int lg = lane >> 4;
  const int wr = (wave >> 1) * 32;
  const int wc = (wave & 1) * 64;

  const int g = blockIdx.x;
  const int v = (g & 7) * 32 + (g >> 3);
  const int bx = v & 7;
  const int by = v >> 3;
  const long brow = (long)by * 64;
  const int bcol = bx * 128;

  const int pcx = lg ^ ((lr >> 1) & 3);

  f32x4 acc[2][4];
#pragma unroll
  for (int m = 0; m < 2; ++m)
#pragma unroll
    for (int n = 0; n < 4; ++n) acc[m][n] = (f32x4){0.f, 0.f, 0.f, 0.f};

  const int rA = tid >> 2;
  const int lc = (tid & 3) ^ ((tid >> 3) & 3);
  const int offA = (tid & ~63) * 16;
  const int rB1 = 64 + (tid >> 2);
  const int offB1 = 4096 + offA;

  for (int k0 = 0; k0 < ADIM; k0 += 32) {
    gload_lds16(A + (brow + rA) * (long)ADIM + k0 + lc * 8, (char*)lsA + offA);
    gload_lds16(Bt + (long)(bcol + rA) * ADIM + k0 + lc * 8, (char*)lsB + offA);
    gload_lds16(Bt + (long)(bcol + rB1) * ADIM + k0 + lc * 8, (char*)lsB + offB1);
    __syncthreads();

    bf16x8 af[2], bf[4];
#pragma unroll
    for (int m = 0; m < 2; ++m)
      af[m] = *(const bf16x8*)((char*)lsA + (wr + m * 16 + lr) * 64 + pcx * 16);
#pragma unroll
    for (int n = 0; n < 4; ++n)
      bf[n] = *(const bf16x8*)((char*)lsB + (wc + n * 16 + lr) * 64 + pcx * 16);
#pragma unroll
    for (int m = 0; m < 2; ++m)
#pragma unroll
      for (int n = 0; n < 4; ++n)
        acc[m][n] = mfma16(bf[n], af[m], acc[m][n]);
    __syncthreads();
  }

#pragma unroll
  for (int m = 0; m < 2; ++m) {
    long row = brow + wr + m * 16 + lr;
#pragma unroll
    for (int n = 0; n < 4; ++n) {
      int coln = bcol + wc + n * 16 + lg * 4;
      float4 bv = *(const float4*)(bias + coln);
      float4 o;
      o.x = acc[m][n][0] + bv.x;
      o.y = acc[m][n][1] + bv.y;
      o.z = acc[m][n][2] + bv.z;
      o.w = acc[m][n][3] + bv.w;
      *(float4*)(C + row * (long)D_ + coln) = o;
    }
  }
}

// ---------------------------------------------------------------------------
// Flash attention (frozen): one block per (bt,h), 4 waves x 16 q-rows,
// 33 j-tiles, dbuf kl/vtf -> ONE barrier/tile, swapped QK^T softmax,
// register K/V prefetch, setprio around MFMA clusters.  BW-bound (~83%).
__global__ __launch_bounds__(256) void attn_kernel(const ushort* __restrict__ q,
                                                   const ushort* __restrict__ kv,
                                                   ushort* __restrict__ o) {
  const int blk = blockIdx.x;
  const int bt = blk >> 4;
  const int h = blk & 15;
  const int tid = threadIdx.x;
  const int wave = tid >> 6;
  const int lane = tid & 63;
  const int lr = lane & 15;
  const int lg = lane >> 4;

  __shared__ ushort klb[2][64 * 64];
  __shared__ ushort vtb[2][64 * 72];
  __shared__ ushort pl[4][16][72];

  const ushort* qbase = q + (size_t)(bt * 64 + wave * 16) * ADIM + h * HD;
  bf16x8 qf[2];
#pragma unroll
  for (int ks = 0; ks < 2; ++ks)
    qf[ks] = *(const bf16x8*)(qbase + (size_t)lr * ADIM + ks * 32 + lg * 8);

  const ushort* kvb = kv + (size_t)bt * NKV * 2048;
  const int jj = tid >> 2;
  const int q4 = tid & 3;

  f32x4 accO[4];
#pragma unroll
  for (int n = 0; n < 4; ++n) accO[n] = (f32x4){0.f, 0.f, 0.f, 0.f};
  float mrun = -1e30f;
  float lrun = 0.f;

  bf16x8 kr0, kr1, vr0, vr1;
  {
    const ushort* src = kvb + (size_t)jj * 2048 + h * HD + q4 * 16;
    kr0 = *(const bf16x8*)(src);
    kr1 = *(const bf16x8*)(src + 8);
    vr0 = *(const bf16x8*)(src + ADIM);
    vr1 = *(const bf16x8*)(src + ADIM + 8);
  }

  for (int jt = 0; jt < NKV / 64; ++jt) {
    const int pb = jt & 1;
    ushort* kl = klb[pb];
    ushort* vtf = vtb[pb];

    {
      int p0 = (q4 * 2) ^ (jj & 7);
      int p1 = (q4 * 2 + 1) ^ (jj & 7);
      *(bf16x8*)((char*)kl + jj * 128 + p0 * 16) = kr0;
      *(bf16x8*)((char*)kl + jj * 128 + p1 * 16) = kr1;
      int d0 = q4 * 16;
      int jc = jj >> 3, jb = jj & 7;
#pragma unroll
      for (int e = 0; e < 8; ++e) {
        vtf[(d0 + e) * 72 + (jc ^ (e & 7)) * 8 + jb] = ((const ushort*)&vr0)[e];
        vtf[(d0 + 8 + e) * 72 + (jc ^ (e & 7)) * 8 + jb] = ((const ushort*)&vr1)[e];
      }
    }

    bf16x8 nk0, nk1, nv0, nv1;
    {
      const int tn = (jt + 1 < NKV / 64) ? jt + 1 : jt;
      const ushort* src = kvb + (size_t)(tn * 64 + jj) * 2048 + h * HD + q4 * 16;
      nk0 = *(const bf16x8*)(src);
      nk1 = *(const bf16x8*)(src + 8);
      nv0 = *(const bf16x8*)(src + ADIM);
      nv1 = *(const bf16x8*)(src + ADIM + 8);
    }
    __syncthreads();

    f32x4 s[4];
#pragma unroll
    for (int nj = 0; nj < 4; ++nj) s[nj] = (f32x4){0.f, 0.f, 0.f, 0.f};
    __builtin_amdgcn_s_setprio(1);
#pragma unroll
    for (int nj = 0; nj < 4; ++nj)
#pragma unroll
      for (int ks = 0; ks < 2; ++ks) {
        int row = nj * 16 + lr;
        int phys = (4 * ks + lg) ^ (lr & 7);
        bf16x8 kf = *(const bf16x8*)((char*)kl + row * 128 + phys * 16);
        s[nj] = mfma16(kf, qf[ks], s[nj]);
      }
    __builtin_amdgcn_s_setprio(0);

    float mloc = s[0][0];
#pragma unroll
    for (int nj = 0; nj < 4; ++nj)
#pragma unroll
      for (int r = 0; r < 4; ++r) mloc = fmaxf(mloc, s[nj][r]);
    mloc = fmaxf(mloc, __shfl_xor(mloc, 16, 64));
    mloc = fmaxf(mloc, __shfl_xor(mloc, 32, 64));
    float mn = fmaxf(mrun, mloc);
    float corr = __expf(mrun - mn);
    mrun = mn;
    float ps = 0.f;
#pragma unroll
    for (int nj = 0; nj < 4; ++nj)
#pragma unroll
      for (int r = 0; r < 4; ++r) {
        float pv = __expf(s[nj][r] - mn);
        s[nj][r] = pv;
        ps += pv;
      }
    ps += __shfl_xor(ps, 16, 64);
    ps += __shfl_xor(ps, 32, 64);
    lrun = lrun * corr + ps;
    float corrq[4];
#pragma unroll
    for (int r = 0; r < 4; ++r) corrq[r] = __shfl(corr, lg * 4 + r, 64);
#pragma unroll
    for (int n = 0; n < 4; ++n)
#pragma unroll
      for (int r = 0; r < 4; ++r) accO[n][r] *= corrq[r];

#pragma unroll
    for (int nj = 0; nj < 4; ++nj)
#pragma unroll
      for (int r = 0; r < 4; ++r)
        pl[wave][lr][nj * 16 + 4 * lg + r] = f2bf(s[nj][r]);

    bf16x8 pf[2];
#pragma unroll
    for (int ks = 0; ks < 2; ++ks)
      pf[ks] = *(const bf16x8*)&pl[wave][lr][ks * 32 + lg * 8];
    __builtin_amdgcn_s_setprio(1);
#pragma unroll
    for (int nd = 0; nd < 4; ++nd)
#pragma unroll
      for (int ks = 0; ks < 2; ++ks) {
        bf16x8 vf = *(const bf16x8*)&vtf[(nd * 16 + lr) * 72 +
                                         ((4 * ks + lg) ^ (lr & 7)) * 8];
        accO[nd] = mfma16(pf[ks], vf, accO[nd]);
      }
    __builtin_amdgcn_s_setprio(0);

    kr0 = nk0; kr1 = nk1; vr0 = nv0; vr1 = nv1;
  }

  float lq[4];
#pragma unroll
  for (int r = 0; r < 4; ++r) lq[r] = __shfl(lrun, lg * 4 + r, 64);
#pragma unroll
  for (int nd = 0; nd < 4; ++nd)
#pragma unroll
    for (int r = 0; r < 4; ++r) {
      float vv = accO[nd][r] / lq[r];
      int row = bt * 64 + wave * 16 + lg * 4 + r;
      o[(size_t)row * ADIM + h * HD + nd * 16 + lr] = f2bf(vv);
    }
}

// ---------------------------------------------------------------------------
extern "C" void kernel_launch(void* const* d_in, const int* in_sizes, int n_in,
                              void* d_out, int out_size, void* d_ws, size_t ws_size,
                              hipStream_t stream) {
  const float* latents = (const float*)d_in[0];
  const float* x = (const float*)d_in[1];
  const float* Wq = (const float*)d_in[2];
  const float* Wkv = (const float*)d_in[3];
  const float* Wout = (const float*)d_in[4];
  const float* bout = (const float*)d_in[5];
  const float* lnl_w = (const float*)d_in[6];
  const float* lnl_b = (const float*)d_in[7];
  const float* lnm_w = (const float*)d_in[8];
  const float* lnm_b = (const float*)d_in[9];

  char* ws = (char*)d_ws;
  size_t off = 0;
  auto alloc = [&](size_t bytes) -> void* {
    void* p = ws + off;
    off += (bytes + 255) & ~(size_t)255;
    return p;
  };
  ushort* kvin = (ushort*)alloc((size_t)BT * NKV * D_ * 2);
  ushort* kvo  = (ushort*)alloc((size_t)BT * NKV * 2048 * 2);
  ushort* qb   = (ushort*)alloc((size_t)BT * NLAT * ADIM * 2);
  ushort* ao   = (ushort*)alloc((size_t)BT * NLAT * ADIM * 2);
  ushort* WqT  = (ushort*)alloc((size_t)D_ * ADIM * 2);
  ushort* WkvT = (ushort*)alloc((size_t)D_ * 2 * ADIM * 2);
  ushort* WoutT = (ushort*)alloc((size_t)ADIM * D_ * 2);

  // 1) LN + all weight transposes in ONE launch
  prep_kernel<<<dim3(PREPBLK), 256, 0, stream>>>(
      latents, x, lnl_w, lnl_b, lnm_w, lnm_b, kvin,
      Wq, Wkv, Wout, WqT, WkvT, WoutT);

  // 2) kv = kv_in @ Wkv  AND  q = lat_ln @ Wq (one grid)
  gemm_big<<<dim3(NWGB), 512, 0, stream>>>(kvin, WkvT, WqT, kvo, qb);

  // 3) attention
  attn_kernel<<<BT * HEADS, 256, 0, stream>>>(qb, kvo, ao);

  // 4) out = ao @ Wout + bout
  gemm_out<<<dim3(256), 256, 0, stream>>>(ao, WoutT, (float*)d_out, bout);
}